// Round 1
// baseline (20697.694 us; speedup 1.0000x reference)
//
#include <hip/hip_runtime.h>
#include <cfloat>
#include <cstdint>

#define N_PTS 16384
#define KNN_K 16
#define KNN_TILE 512
#define CERT_EPS 3e-6f

// ---------------------------------------------------------------------------
// FPS shared block. Coordinates now live in per-thread REGISTERS (xr/yr/zr);
// only the per-wave reduction slots live in LDS (parity double-buffered,
// exactly one writer per slot -> no atomics, no resets, ONE barrier/iter).
// ---------------------------------------------------------------------------
struct FpsSmem {
    unsigned long long wkey[2][16];  // per-wave packed (m1, ~g1) winner key
    float wm2[2][16];                // per-wave exact second max
    float4 wxyz[2][16];              // per-wave winner coords (posted by owner lane)
    int cand_idx[64];
    int cand_cnt;
    int more_flag;
    double red_d[16];
};

// Exact per-wave top-2 butterfly (comparisons only -> bit-identical to the
// validated packed-key atomicMax total order: larger m1, tie -> smaller g).
// All lanes converge; lane 0 posts (key,m2); the lane OWNING the winning
// point posts its xyz from registers.
template <int P>
__device__ __forceinline__ void post_wave_top2(FpsSmem& sm, int p, int wave, int lane, int tid,
                                               float m1, float m2, int g1,
                                               const float* xr, const float* yr, const float* zr) {
    const int g1o = g1;
#pragma unroll
    for (int off = 1; off < 64; off <<= 1) {
        const float om1 = __shfl_xor(m1, off);
        const float om2 = __shfl_xor(m2, off);
        const int og = __shfl_xor(g1, off);
        const bool sw = (om1 > m1) || (om1 == m1 && og < g1);
        const float lm1 = sw ? m1 : om1;          // loser's max
        m2 = fmaxf(sw ? om2 : m2, lm1);           // winner's m2 vs loser's m1
        m1 = sw ? om1 : m1;
        g1 = sw ? og : g1;
    }
    if (lane == 0) {
        sm.wkey[p][wave] = ((unsigned long long)__float_as_uint(m1) << 32) |
                           (unsigned long long)(~(unsigned)g1);
        sm.wm2[p][wave] = m2;
    }
    if (g1o == g1) {  // unique owner thread of the wave-winning point
        const int qw = (g1 - tid) >> 10;  // /1024
        float xw = 0.0f, yw = 0.0f, zw = 0.0f;
#pragma unroll
        for (int q = 0; q < P; ++q)
            if (q == qw) { xw = xr[q]; yw = yr[q]; zw = zr[q]; }
        sm.wxyz[p][wave] = make_float4(xw, yw, zw, 0.0f);
    }
}

// ---------------------------------------------------------------------------
// FPS body, one-barrier-per-iteration restructure. Distance-update numerics
// verbatim (fp32 fmaf form, per-thread top-2). Selection = identical total
// order as validated atomicMax. Certification: fallback iff global second
// max >= thr, which is EXACTLY equivalent to the validated
// (#threads m1>=thr)>1 || winner_m2>=thr. fp64 fallback verbatim.
// ---------------------------------------------------------------------------
template <int P, bool IND>
__device__ __forceinline__ void fps_body(FpsSmem& sm, const float* __restrict__ pts,
                                         const int* __restrict__ idx,
                                         int n_out, int* __restrict__ fi) {
    constexpr int T = 1024;
    constexpr int NW = T / 64;
    const int tid = threadIdx.x;
    const int wave = tid >> 6, lane = tid & 63;

    __syncthreads();  // guard smem reuse against the previous stage's reads

    float xr[P], yr[P], zr[P], c[P];
    {
        // prologue: load coords, update vs sample 0, reduce, post parity 1
        const int g0 = IND ? idx[0] : 0;
        const float sx = pts[g0 * 3 + 0], sy = pts[g0 * 3 + 1], sz = pts[g0 * 3 + 2];
        if (tid == 0) fi[0] = g0;
#pragma unroll
        for (int q = 0; q < P; ++q) {
            const int g = tid + q * T;
            const int gg = IND ? idx[g] : g;
            xr[q] = pts[gg * 3 + 0];
            yr[q] = pts[gg * 3 + 1];
            zr[q] = pts[gg * 3 + 2];
            c[q] = FLT_MAX;
        }
        float m1 = -1.0f, m2 = -1.0f;
        int g1 = 0x7fffffff;
#pragma unroll
        for (int q = 0; q < P; ++q) {
            const float dx = xr[q] - sx, dy = yr[q] - sy, dz = zr[q] - sz;
            const float t = fmaf(dx, dx, fmaf(dy, dy, dz * dz));
            const float nc = fminf(c[q], t);
            c[q] = nc;
            const bool gt = nc > m1;
            m2 = fmaxf(m2, fminf(nc, m1));
            m1 = fmaxf(m1, nc);
            g1 = gt ? (tid + q * T) : g1;
        }
        post_wave_top2<P>(sm, 1, wave, lane, tid, m1, m2, g1, xr, yr, zr);
    }

    for (int s = 1; s < n_out; ++s) {
        __syncthreads();  // the single barrier: makes parity (s&1) slots visible
        const int par = s & 1;

        // cross-wave top-2 over the 16 posted keys (broadcast LDS reads)
        unsigned long long bk = sm.wkey[par][0], bk2 = 0ull;
        int bw = 0;
#pragma unroll
        for (int w = 1; w < NW; ++w) {
            const unsigned long long v = sm.wkey[par][w];
            const bool gtb = v > bk;
            bk2 = gtb ? bk : (v > bk2 ? v : bk2);
            bw = gtb ? w : bw;
            bk = gtb ? v : bk;
        }
        const float M1 = __uint_as_float((unsigned)(bk >> 32));
        int G1 = (int)(~(unsigned)bk);
        const float thr = M1 - M1 * CERT_EPS;
        // exact global second max = max(best non-winning wave m1, winner wave m2)
        const float M2 = fmaxf(__uint_as_float((unsigned)(bk2 >> 32)), sm.wm2[par][bw]);
        float4 wc = sm.wxyz[par][bw];

        if (M2 >= thr) {
            // ---- cooperative exact fp64 fallback (uniform branch, verbatim) ----
            unsigned miss = 0;
#pragma unroll
            for (int q = 0; q < P; ++q)
                if (c[q] >= thr) miss |= (1u << q);
            double BD = -1.0;
            int BG = 0x7fffffff;
            for (;;) {
                if (tid == 0) { sm.cand_cnt = 0; sm.more_flag = 0; }
                __syncthreads();
#pragma unroll
                for (int q = 0; q < P; ++q) {
                    if (miss & (1u << q)) {
                        int slot = atomicAdd(&sm.cand_cnt, 1);
                        if (slot < 64) {
                            sm.cand_idx[slot] = tid + q * T;
                            miss &= ~(1u << q);
                        } else {
                            sm.more_flag = 1;
                        }
                    }
                }
                __syncthreads();
                int ncand = sm.cand_cnt;
                if (ncand > 64) ncand = 64;
                for (int ci = 0; ci < ncand; ++ci) {
                    const int g = sm.cand_idx[ci];
                    const int gg = IND ? idx[g] : g;
                    const double qx = (double)pts[gg * 3 + 0];
                    const double qy = (double)pts[gg * 3 + 1];
                    const double qz = (double)pts[gg * 3 + 2];
                    double dmin = DBL_MAX;
                    for (int i = tid; i < s; i += T) {
                        const int h = fi[i];  // original index, any stage
                        double ddx = qx - (double)pts[h * 3 + 0];
                        double ddy = qy - (double)pts[h * 3 + 1];
                        double ddz = qz - (double)pts[h * 3 + 2];
                        double dd = ddx * ddx + ddy * ddy + ddz * ddz;
                        dmin = (dd < dmin) ? dd : dmin;
                    }
                    for (int off = 32; off; off >>= 1) {
                        double od = __shfl_xor(dmin, off);
                        dmin = (od < dmin) ? od : dmin;
                    }
                    if (lane == 0) sm.red_d[wave] = dmin;
                    __syncthreads();
                    double dall = sm.red_d[0];
#pragma unroll
                    for (int w = 1; w < NW; ++w) dall = (sm.red_d[w] < dall) ? sm.red_d[w] : dall;
                    if (dall > BD || (dall == BD && g < BG)) { BD = dall; BG = g; }
                    __syncthreads();
                }
                int mf = sm.more_flag;
                __syncthreads();
                if (!mf) break;
            }
            G1 = BG;
            const int wg = IND ? idx[G1] : G1;
            wc = make_float4(pts[wg * 3 + 0], pts[wg * 3 + 1], pts[wg * 3 + 2], 0.0f);
        }

        if (tid == 0) fi[s] = IND ? idx[G1] : G1;
        if (s == n_out - 1) break;

        // fused min-update + per-thread top-2 (validated numerics, verbatim)
        const float sx = wc.x, sy = wc.y, sz = wc.z;
        float m1 = -1.0f, m2 = -1.0f;
        int g1 = 0x7fffffff;
#pragma unroll
        for (int q = 0; q < P; ++q) {
            const float dx = xr[q] - sx, dy = yr[q] - sy, dz = zr[q] - sz;
            const float t = fmaf(dx, dx, fmaf(dy, dy, dz * dz));
            const float nc = fminf(c[q], t);
            c[q] = nc;
            const bool gt = nc > m1;
            m2 = fmaxf(m2, fminf(nc, m1));
            m1 = fmaxf(m1, nc);
            g1 = gt ? (tid + q * T) : g1;
        }
        post_wave_top2<P>(sm, par ^ 1, wave, lane, tid, m1, m2, g1, xr, yr, zr);
    }
}

// ---------------------------------------------------------------------------
// Fused KNN + EdgeConv body: 1024 threads = 16 waves = 16 query points.
// Per-wave fp64-exact top-16 (verbatim validated numerics), edgeconv inline.
// ---------------------------------------------------------------------------
struct KnnSmem {
    float sx[KNN_TILE], sy[KNN_TILE], sz[KNN_TILE];
    float w1[6 * 64], b1v[64], w2[64 * 64], b2v[64];
};

__device__ __forceinline__ void knn_edge_body(
    KnnSmem& sm, const float* __restrict__ pts,
    const float* __restrict__ ew1, const float* __restrict__ eb1,
    const float* __restrict__ ew2, const float* __restrict__ eb2,
    float* __restrict__ feats, int qb) {
    for (int t = threadIdx.x; t < 6 * 64; t += 1024) sm.w1[t] = ew1[t];
    for (int t = threadIdx.x; t < 64; t += 1024) { sm.b1v[t] = eb1[t]; sm.b2v[t] = eb2[t]; }
    for (int t = threadIdx.x; t < 64 * 64; t += 1024) sm.w2[t] = ew2[t];

    const int wave = threadIdx.x >> 6;
    const int lane = threadIdx.x & 63;
    const int qi = qb * 16 + wave;
    const double qxd = (double)pts[qi * 3 + 0];
    const double qyd = (double)pts[qi * 3 + 1];
    const double qzd = (double)pts[qi * 3 + 2];

    double ld[16];
    int li[16];
#pragma unroll
    for (int s = 0; s < 16; ++s) { ld[s] = DBL_MAX; li[s] = 0x7fffffff; }
    double md = DBL_MAX; int mj = 0x7fffffff; int mslot = 0;

    for (int t0 = 0; t0 < N_PTS; t0 += KNN_TILE) {
        __syncthreads();
        for (int t = threadIdx.x; t < KNN_TILE; t += 1024) {
            sm.sx[t] = pts[(t0 + t) * 3 + 0];
            sm.sy[t] = pts[(t0 + t) * 3 + 1];
            sm.sz[t] = pts[(t0 + t) * 3 + 2];
        }
        __syncthreads();
#pragma unroll
        for (int m = 0; m < KNN_TILE / 64; ++m) {
            const int cc = lane + m * 64;
            const int j = t0 + cc;
            if (j == qi) continue;  // diagonal excluded (d=inf in reference)
            double dx = qxd - (double)sm.sx[cc];
            double dy = qyd - (double)sm.sy[cc];
            double dz = qzd - (double)sm.sz[cc];
            double dd = dx * dx + dy * dy + dz * dz;
            if (dd < md || (dd == md && j < mj)) {
#pragma unroll
                for (int s = 0; s < 16; ++s)
                    if (s == mslot) { ld[s] = dd; li[s] = j; }
                md = -1.0; mj = -1; mslot = 0;
#pragma unroll
                for (int s = 0; s < 16; ++s) {
                    bool g = (ld[s] > md) || (ld[s] == md && li[s] > mj);
                    if (g) { md = ld[s]; mj = li[s]; mslot = s; }
                }
            }
        }
    }

    const float xi = pts[qi * 3], yi = pts[qi * 3 + 1], zi = pts[qi * 3 + 2];
    float acc = -FLT_MAX;
    for (int r = 0; r < KNN_K; ++r) {
        double cd = DBL_MAX; int cj = 0x7fffffff; int cs = 0;
#pragma unroll
        for (int s = 0; s < 16; ++s) {
            bool l = (ld[s] < cd) || (ld[s] == cd && li[s] < cj);
            if (l) { cd = ld[s]; cj = li[s]; cs = s; }
        }
        double wd = cd; int wj = cj;
        for (int off = 32; off; off >>= 1) {
            double od = __shfl_xor(wd, off);
            int oj = __shfl_xor(wj, off);
            if (od < wd || (od == wd && oj < wj)) { wd = od; wj = oj; }
        }
        if (cd == wd && cj == wj) {
#pragma unroll
            for (int s = 0; s < 16; ++s)
                if (s == cs) { ld[s] = DBL_MAX; li[s] = 0x7fffffff; }
        }
        const float xj = pts[wj * 3], yj = pts[wj * 3 + 1], zj = pts[wj * 3 + 2];
        const float f3 = xj - xi, f4 = yj - yi, f5 = zj - zi;
        float h1 = sm.b1v[lane];
        h1 = fmaf(xi, sm.w1[0 * 64 + lane], h1);
        h1 = fmaf(yi, sm.w1[1 * 64 + lane], h1);
        h1 = fmaf(zi, sm.w1[2 * 64 + lane], h1);
        h1 = fmaf(f3, sm.w1[3 * 64 + lane], h1);
        h1 = fmaf(f4, sm.w1[4 * 64 + lane], h1);
        h1 = fmaf(f5, sm.w1[5 * 64 + lane], h1);
        h1 = fmaxf(h1, 0.0f);
        float h2 = sm.b2v[lane];
        for (int d = 0; d < 64; ++d)
            h2 = fmaf(__shfl(h1, d), sm.w2[d * 64 + lane], h2);
        acc = fmaxf(acc, h2);
    }
    feats[qi * 64 + lane] = acc;
}

// ---------------------------------------------------------------------------
// Mega kernel: block 0 chains fps0 -> fps1 -> fps2 (coords register-resident;
// fi* = ORIGINAL indices) and writes sp0/sp1/sp2. Blocks 1..1024 = fused
// knn+edgeconv (hidden under fps). Static LDS is now max(Fps,Knn) ~= 25 KB,
// so KNN blocks reach 2 blocks/CU (wave-limited) instead of 1 (LDS-limited).
// ---------------------------------------------------------------------------
__global__ __launch_bounds__(1024)
void mega_kernel(const float* __restrict__ pts,
                 const float* __restrict__ ew1, const float* __restrict__ eb1,
                 const float* __restrict__ ew2, const float* __restrict__ eb2,
                 float* __restrict__ feats,
                 int* __restrict__ fi0, int* __restrict__ fi1, int* __restrict__ fi2,
                 float* __restrict__ sp0, float* __restrict__ sp1,
                 float* __restrict__ sp2) {
    constexpr size_t SMEM_BYTES =
        sizeof(FpsSmem) > sizeof(KnnSmem) ? sizeof(FpsSmem) : sizeof(KnnSmem);
    __shared__ __align__(16) char raw[SMEM_BYTES];
    if (blockIdx.x == 0) {
        FpsSmem& sm = *reinterpret_cast<FpsSmem*>(raw);
        fps_body<16, false>(sm, pts, nullptr, 4096, fi0);
        fps_body<4, true>(sm, pts, fi0, 1024, fi1);
        fps_body<1, true>(sm, pts, fi1, 256, fi2);
        __syncthreads();
        const int tid = threadIdx.x;
        for (int t = tid; t < 4096; t += 1024) {
            int g = fi0[t];
            sp0[t * 3 + 0] = pts[g * 3 + 0];
            sp0[t * 3 + 1] = pts[g * 3 + 1];
            sp0[t * 3 + 2] = pts[g * 3 + 2];
        }
        if (tid < 1024) {
            int g = fi1[tid];
            sp1[tid * 3 + 0] = pts[g * 3 + 0];
            sp1[tid * 3 + 1] = pts[g * 3 + 1];
            sp1[tid * 3 + 2] = pts[g * 3 + 2];
        }
        if (tid < 256) {
            int g = fi2[tid];
            sp2[tid * 3 + 0] = pts[g * 3 + 0];
            sp2[tid * 3 + 1] = pts[g * 3 + 1];
            sp2[tid * 3 + 2] = pts[g * 3 + 2];
        }
    } else {
        knn_edge_body(*reinterpret_cast<KnnSmem*>(raw), pts, ew1, eb1, ew2, eb2,
                      feats, blockIdx.x - 1);
    }
}

// ---------------------------------------------------------------------------
// Tail: all three MLPs in one launch (validated mlp numerics, verbatim).
// ---------------------------------------------------------------------------
__device__ __forceinline__ void mlp_body(
    const float* __restrict__ feats, const int* __restrict__ orig,
    const float* __restrict__ mw1, const float* __restrict__ mb1,
    const float* __restrict__ mw2, const float* __restrict__ mb2,
    float* __restrict__ outp, int pb) {
    __shared__ float sfl[64], h1l[128];
    const int t = threadIdx.x;
    for (int pl = 0; pl < 16; ++pl) {
        const int p = pb * 16 + pl;
        const int g = orig[p];
        if (t < 64) sfl[t] = feats[g * 64 + t];
        __syncthreads();
        if (t < 128) {
            float h = mb1[t];
            for (int dd = 0; dd < 64; ++dd)
                h = fmaf(sfl[dd], mw1[dd * 128 + t], h);
            h1l[t] = fmaxf(h, 0.0f);
        }
        __syncthreads();
        float o = mb2[t];
        for (int dd = 0; dd < 128; ++dd)
            o = fmaf(h1l[dd], mw2[dd * 256 + t], o);
        outp[p * 256 + t] = o;
        __syncthreads();
    }
}

__global__ __launch_bounds__(256) void tail_kernel(
    const float* __restrict__ feats,
    const int* __restrict__ fi0, const int* __restrict__ fi1,
    const int* __restrict__ fi2,
    const float* __restrict__ mw1, const float* __restrict__ mb1,
    const float* __restrict__ mw2, const float* __restrict__ mb2,
    float* __restrict__ out) {
    const int b = blockIdx.x;
    float* lf0 = out + 12288;
    float* lf1 = out + 1063936;
    float* lf2 = out + 1326848;
    if (b < 256) {
        mlp_body(feats, fi0, mw1 + 0 * 8192, mb1 + 0 * 128,
                 mw2 + 0 * 32768, mb2 + 0 * 256, lf0, b);
    } else if (b < 320) {
        mlp_body(feats, fi1, mw1 + 1 * 8192, mb1 + 1 * 128,
                 mw2 + 1 * 32768, mb2 + 1 * 256, lf1, b - 256);
    } else {
        mlp_body(feats, fi2, mw1 + 2 * 8192, mb1 + 2 * 128,
                 mw2 + 2 * 32768, mb2 + 2 * 256, lf2, b - 320);
    }
}

// ---------------------------------------------------------------------------
extern "C" void kernel_launch(void* const* d_in, const int* in_sizes, int n_in,
                              void* d_out, int out_size, void* d_ws, size_t ws_size,
                              hipStream_t stream) {
    const float* pts = (const float*)d_in[0];
    const float* ew1 = (const float*)d_in[1];
    const float* eb1 = (const float*)d_in[2];
    const float* ew2 = (const float*)d_in[3];
    const float* eb2 = (const float*)d_in[4];
    const float* mw1 = (const float*)d_in[5];  // (3,64,128)
    const float* mb1 = (const float*)d_in[6];  // (3,128)
    const float* mw2 = (const float*)d_in[7];  // (3,128,256)
    const float* mb2 = (const float*)d_in[8];  // (3,256)
    float* out = (float*)d_out;
    char* ws = (char*)d_ws;

    float* feats = (float*)(ws + 0);           // 16384*64*4 = 4 MB
    int* fi0 = (int*)(ws + 4194304);           // 4096 ints (original indices)
    int* fi1 = (int*)(ws + 4210688);           // 1024 ints (original indices)
    int* fi2 = (int*)(ws + 4214784);           // 256 ints  (original indices)

    float* sp0 = out + 0;
    float* sp1 = out + 1060864;
    float* sp2 = out + 1326080;

    mega_kernel<<<1 + N_PTS / 16, 1024, 0, stream>>>(pts, ew1, eb1, ew2, eb2, feats,
                                                     fi0, fi1, fi2, sp0, sp1, sp2);
    tail_kernel<<<336, 256, 0, stream>>>(feats, fi0, fi1, fi2, mw1, mb1, mw2, mb2, out);
}

// Round 2
// 13743.245 us; speedup vs baseline: 1.5060x; 1.5060x over previous
//
#include <hip/hip_runtime.h>
#include <cfloat>
#include <cstdint>

#define N_PTS 16384
#define KNN_K 16
#define KNN_TILE 512
#define CERT_EPS 3e-6f

// ---------------------------------------------------------------------------
// FPS shared block. x,y in LDS (proven 64-VGPR footprint); z and c in
// registers. Per-wave results in parity double-buffered slots, exactly one
// writer per slot -> no atomics, no resets, ONE barrier per iteration.
// ---------------------------------------------------------------------------
struct FpsSmem {
    float2 sxy[N_PTS];               // x,y coords (z stays in registers)
    unsigned long long wkey[2][16];  // per-wave packed (m1, ~g1), parity dbuf
    float wm2[2][16];                // per-wave exact second max
    float wz[2][16];                 // per-wave winner z (owner-published)
    int cand_idx[64];
    int cand_cnt;
    int more_flag;
    double red_d[16];
};

// Exact per-wave top-2 butterfly (comparisons only -> identical total order
// to the validated packed-key reduction: larger m1, tie -> smaller g).
// Lane 0 posts (key,m2); the thread OWNING the winning point posts its z
// (scalar, tracked alongside g1 -- no register-array pointers!).
__device__ __forceinline__ void post_wave_top2(FpsSmem& sm, int p, int wave, int lane,
                                               float m1, float m2, int g1, float zbest) {
    const int g1o = g1;
#pragma unroll
    for (int off = 1; off < 64; off <<= 1) {
        const float om1 = __shfl_xor(m1, off);
        const float om2 = __shfl_xor(m2, off);
        const int og = __shfl_xor(g1, off);
        const bool sw = (om1 > m1) || (om1 == m1 && og < g1);
        const float lm1 = sw ? m1 : om1;          // loser's max
        m2 = fmaxf(sw ? om2 : m2, lm1);           // winner's m2 vs loser's m1
        m1 = sw ? om1 : m1;
        g1 = sw ? og : g1;
    }
    if (lane == 0) {
        sm.wkey[p][wave] = ((unsigned long long)__float_as_uint(m1) << 32) |
                           (unsigned long long)(~(unsigned)g1);
        sm.wm2[p][wave] = m2;
    }
    if (g1o == g1) sm.wz[p][wave] = zbest;  // unique owner of the winning point
}

// ---------------------------------------------------------------------------
// FPS body. Distance-update numerics verbatim (fp32 fmaf form, per-thread
// top-2). Selection = identical total order as validated. Certification:
// fallback iff global second max >= thr (exactly equivalent to validated
// (#threads m1>=thr)>1 || winner_m2>=thr). fp64 fallback verbatim.
// ---------------------------------------------------------------------------
template <int P, bool IND>
__device__ __forceinline__ void fps_body(FpsSmem& sm, const float* __restrict__ pts,
                                         const int* __restrict__ idx,
                                         int n_out, int* __restrict__ fi) {
    constexpr int T = 1024;
    constexpr int NW = T / 64;
    const int tid = threadIdx.x;
    const int wave = tid >> 6, lane = tid & 63;

    __syncthreads();  // guard smem reuse against the previous stage's reads

    float zr[P], c[P];
    {
        // prologue: load coords (x,y -> LDS, z -> reg), update vs sample 0,
        // reduce, post into parity-1 slots
        const int g0 = IND ? idx[0] : 0;
        const float sx = pts[g0 * 3 + 0], sy = pts[g0 * 3 + 1], sz = pts[g0 * 3 + 2];
        if (tid == 0) fi[0] = g0;
        float m1 = -1.0f, m2 = -1.0f;
        int g1 = 0x7fffffff;
        float zbest = 0.0f;
#pragma unroll
        for (int q = 0; q < P; ++q) {
            const int g = tid + q * T;
            const int gg = IND ? idx[g] : g;
            const float x = pts[gg * 3 + 0];
            const float y = pts[gg * 3 + 1];
            const float z = pts[gg * 3 + 2];
            sm.sxy[g] = make_float2(x, y);
            zr[q] = z;
            const float dx = x - sx, dy = y - sy, dz = z - sz;
            const float t = fmaf(dx, dx, fmaf(dy, dy, dz * dz));
            const float nc = fminf(FLT_MAX, t);
            c[q] = nc;
            const bool gt = nc > m1;
            m2 = fmaxf(m2, fminf(nc, m1));
            m1 = fmaxf(m1, nc);
            g1 = gt ? g : g1;
            zbest = gt ? z : zbest;
        }
        post_wave_top2(sm, 1, wave, lane, m1, m2, g1, zbest);
    }

    for (int s = 1; s < n_out; ++s) {
        __syncthreads();  // the single barrier: makes parity (s&1) slots visible
        const int par = s & 1;

        // lane-parallel merge of the 16 wave slots: lane L owns slot L&15,
        // 4-level butterfly carrying (key, m2, z). All 64 lanes converge to
        // the identical global result -- uniform across the block.
        const int sl = lane & 15;
        unsigned long long k = sm.wkey[par][sl];
        float q2 = sm.wm2[par][sl];
        float qz = sm.wz[par][sl];
#pragma unroll
        for (int off = 1; off < 16; off <<= 1) {
            const unsigned long long ok = __shfl_xor(k, off);
            const float oq2 = __shfl_xor(q2, off);
            const float oqz = __shfl_xor(qz, off);
            const bool sw = ok > k;
            const unsigned long long lk = sw ? k : ok;  // loser's key
            const float lm1 = __uint_as_float((unsigned)(lk >> 32));
            q2 = fmaxf(sw ? oq2 : q2, lm1);
            k = sw ? ok : k;
            qz = sw ? oqz : qz;
        }
        const float M1 = __uint_as_float((unsigned)(k >> 32));
        int G1 = (int)(~(unsigned)k);
        const float thr = M1 - M1 * CERT_EPS;
        const float M2 = q2;

        float nsx, nsy, nsz;
        if (M2 >= thr) {
            // ---- cooperative exact fp64 fallback (uniform branch, verbatim) ----
            unsigned miss = 0;
#pragma unroll
            for (int q = 0; q < P; ++q)
                if (c[q] >= thr) miss |= (1u << q);
            double BD = -1.0;
            int BG = 0x7fffffff;
            for (;;) {
                if (tid == 0) { sm.cand_cnt = 0; sm.more_flag = 0; }
                __syncthreads();
#pragma unroll
                for (int q = 0; q < P; ++q) {
                    if (miss & (1u << q)) {
                        int slot = atomicAdd(&sm.cand_cnt, 1);
                        if (slot < 64) {
                            sm.cand_idx[slot] = tid + q * T;
                            miss &= ~(1u << q);
                        } else {
                            sm.more_flag = 1;
                        }
                    }
                }
                __syncthreads();
                int ncand = sm.cand_cnt;
                if (ncand > 64) ncand = 64;
                for (int ci = 0; ci < ncand; ++ci) {
                    const int g = sm.cand_idx[ci];
                    const int gg = IND ? idx[g] : g;
                    const double qx = (double)pts[gg * 3 + 0];
                    const double qy = (double)pts[gg * 3 + 1];
                    const double qz2 = (double)pts[gg * 3 + 2];
                    double dmin = DBL_MAX;
                    for (int i = tid; i < s; i += T) {
                        const int h = fi[i];  // original index, any stage
                        double ddx = qx - (double)pts[h * 3 + 0];
                        double ddy = qy - (double)pts[h * 3 + 1];
                        double ddz = qz2 - (double)pts[h * 3 + 2];
                        double dd = ddx * ddx + ddy * ddy + ddz * ddz;
                        dmin = (dd < dmin) ? dd : dmin;
                    }
                    for (int off = 32; off; off >>= 1) {
                        double od = __shfl_xor(dmin, off);
                        dmin = (od < dmin) ? od : dmin;
                    }
                    if (lane == 0) sm.red_d[wave] = dmin;
                    __syncthreads();
                    double dall = sm.red_d[0];
#pragma unroll
                    for (int w = 1; w < NW; ++w) dall = (sm.red_d[w] < dall) ? sm.red_d[w] : dall;
                    if (dall > BD || (dall == BD && g < BG)) { BD = dall; BG = g; }
                    __syncthreads();
                }
                int mf = sm.more_flag;
                __syncthreads();
                if (!mf) break;
            }
            G1 = BG;
            const int wg = IND ? idx[G1] : G1;
            nsx = pts[wg * 3 + 0];
            nsy = pts[wg * 3 + 1];
            nsz = pts[wg * 3 + 2];
        } else {
            const float2 xy = sm.sxy[G1];  // broadcast read (uniform address)
            nsx = xy.x;
            nsy = xy.y;
            nsz = qz;  // carried with the winning key through the merge
        }

        if (tid == 0) fi[s] = IND ? idx[G1] : G1;
        if (s == n_out - 1) break;

        // fused min-update + per-thread top-2 (validated numerics, verbatim)
        float m1 = -1.0f, m2 = -1.0f;
        int g1 = 0x7fffffff;
        float zbest = 0.0f;
#pragma unroll
        for (int q = 0; q < P; ++q) {
            const float2 xy = sm.sxy[tid + q * T];
            const float dx = xy.x - nsx, dy = xy.y - nsy, dz = zr[q] - nsz;
            const float t = fmaf(dx, dx, fmaf(dy, dy, dz * dz));
            const float nc = fminf(c[q], t);
            c[q] = nc;
            const bool gt = nc > m1;
            m2 = fmaxf(m2, fminf(nc, m1));
            m1 = fmaxf(m1, nc);
            g1 = gt ? (tid + q * T) : g1;
            zbest = gt ? zr[q] : zbest;
        }
        post_wave_top2(sm, par ^ 1, wave, lane, m1, m2, g1, zbest);
    }
}

// ---------------------------------------------------------------------------
// Fused KNN + EdgeConv body: 1024 threads = 16 waves = 16 query points.
// Per-wave fp64-exact top-16 (verbatim validated numerics), edgeconv inline.
// ---------------------------------------------------------------------------
struct KnnSmem {
    float sx[KNN_TILE], sy[KNN_TILE], sz[KNN_TILE];
    float w1[6 * 64], b1v[64], w2[64 * 64], b2v[64];
};

__device__ __forceinline__ void knn_edge_body(
    KnnSmem& sm, const float* __restrict__ pts,
    const float* __restrict__ ew1, const float* __restrict__ eb1,
    const float* __restrict__ ew2, const float* __restrict__ eb2,
    float* __restrict__ feats, int qb) {
    for (int t = threadIdx.x; t < 6 * 64; t += 1024) sm.w1[t] = ew1[t];
    for (int t = threadIdx.x; t < 64; t += 1024) { sm.b1v[t] = eb1[t]; sm.b2v[t] = eb2[t]; }
    for (int t = threadIdx.x; t < 64 * 64; t += 1024) sm.w2[t] = ew2[t];

    const int wave = threadIdx.x >> 6;
    const int lane = threadIdx.x & 63;
    const int qi = qb * 16 + wave;
    const double qxd = (double)pts[qi * 3 + 0];
    const double qyd = (double)pts[qi * 3 + 1];
    const double qzd = (double)pts[qi * 3 + 2];

    double ld[16];
    int li[16];
#pragma unroll
    for (int s = 0; s < 16; ++s) { ld[s] = DBL_MAX; li[s] = 0x7fffffff; }
    double md = DBL_MAX; int mj = 0x7fffffff; int mslot = 0;

    for (int t0 = 0; t0 < N_PTS; t0 += KNN_TILE) {
        __syncthreads();
        for (int t = threadIdx.x; t < KNN_TILE; t += 1024) {
            sm.sx[t] = pts[(t0 + t) * 3 + 0];
            sm.sy[t] = pts[(t0 + t) * 3 + 1];
            sm.sz[t] = pts[(t0 + t) * 3 + 2];
        }
        __syncthreads();
#pragma unroll
        for (int m = 0; m < KNN_TILE / 64; ++m) {
            const int cc = lane + m * 64;
            const int j = t0 + cc;
            if (j == qi) continue;  // diagonal excluded (d=inf in reference)
            double dx = qxd - (double)sm.sx[cc];
            double dy = qyd - (double)sm.sy[cc];
            double dz = qzd - (double)sm.sz[cc];
            double dd = dx * dx + dy * dy + dz * dz;
            if (dd < md || (dd == md && j < mj)) {
#pragma unroll
                for (int s = 0; s < 16; ++s)
                    if (s == mslot) { ld[s] = dd; li[s] = j; }
                md = -1.0; mj = -1; mslot = 0;
#pragma unroll
                for (int s = 0; s < 16; ++s) {
                    bool g = (ld[s] > md) || (ld[s] == md && li[s] > mj);
                    if (g) { md = ld[s]; mj = li[s]; mslot = s; }
                }
            }
        }
    }

    const float xi = pts[qi * 3], yi = pts[qi * 3 + 1], zi = pts[qi * 3 + 2];
    float acc = -FLT_MAX;
    for (int r = 0; r < KNN_K; ++r) {
        double cd = DBL_MAX; int cj = 0x7fffffff; int cs = 0;
#pragma unroll
        for (int s = 0; s < 16; ++s) {
            bool l = (ld[s] < cd) || (ld[s] == cd && li[s] < cj);
            if (l) { cd = ld[s]; cj = li[s]; cs = s; }
        }
        double wd = cd; int wj = cj;
        for (int off = 32; off; off >>= 1) {
            double od = __shfl_xor(wd, off);
            int oj = __shfl_xor(wj, off);
            if (od < wd || (od == wd && oj < wj)) { wd = od; wj = oj; }
        }
        if (cd == wd && cj == wj) {
#pragma unroll
            for (int s = 0; s < 16; ++s)
                if (s == cs) { ld[s] = DBL_MAX; li[s] = 0x7fffffff; }
        }
        const float xj = pts[wj * 3], yj = pts[wj * 3 + 1], zj = pts[wj * 3 + 2];
        const float f3 = xj - xi, f4 = yj - yi, f5 = zj - zi;
        float h1 = sm.b1v[lane];
        h1 = fmaf(xi, sm.w1[0 * 64 + lane], h1);
        h1 = fmaf(yi, sm.w1[1 * 64 + lane], h1);
        h1 = fmaf(zi, sm.w1[2 * 64 + lane], h1);
        h1 = fmaf(f3, sm.w1[3 * 64 + lane], h1);
        h1 = fmaf(f4, sm.w1[4 * 64 + lane], h1);
        h1 = fmaf(f5, sm.w1[5 * 64 + lane], h1);
        h1 = fmaxf(h1, 0.0f);
        float h2 = sm.b2v[lane];
        for (int d = 0; d < 64; ++d)
            h2 = fmaf(__shfl(h1, d), sm.w2[d * 64 + lane], h2);
        acc = fmaxf(acc, h2);
    }
    feats[qi * 64 + lane] = acc;
}

// ---------------------------------------------------------------------------
// Mega kernel: block 0 chains fps0 -> fps1 -> fps2 (x,y LDS-resident;
// fi* = ORIGINAL indices) and writes sp0/sp1/sp2. Blocks 1..1024 = fused
// knn+edgeconv (hidden under fps).
// ---------------------------------------------------------------------------
__global__ __launch_bounds__(1024)
void mega_kernel(const float* __restrict__ pts,
                 const float* __restrict__ ew1, const float* __restrict__ eb1,
                 const float* __restrict__ ew2, const float* __restrict__ eb2,
                 float* __restrict__ feats,
                 int* __restrict__ fi0, int* __restrict__ fi1, int* __restrict__ fi2,
                 float* __restrict__ sp0, float* __restrict__ sp1,
                 float* __restrict__ sp2) {
    constexpr size_t SMEM_BYTES =
        sizeof(FpsSmem) > sizeof(KnnSmem) ? sizeof(FpsSmem) : sizeof(KnnSmem);
    __shared__ __align__(16) char raw[SMEM_BYTES];
    if (blockIdx.x == 0) {
        FpsSmem& sm = *reinterpret_cast<FpsSmem*>(raw);
        fps_body<16, false>(sm, pts, nullptr, 4096, fi0);
        fps_body<4, true>(sm, pts, fi0, 1024, fi1);
        fps_body<1, true>(sm, pts, fi1, 256, fi2);
        __syncthreads();
        const int tid = threadIdx.x;
        for (int t = tid; t < 4096; t += 1024) {
            int g = fi0[t];
            sp0[t * 3 + 0] = pts[g * 3 + 0];
            sp0[t * 3 + 1] = pts[g * 3 + 1];
            sp0[t * 3 + 2] = pts[g * 3 + 2];
        }
        if (tid < 1024) {
            int g = fi1[tid];
            sp1[tid * 3 + 0] = pts[g * 3 + 0];
            sp1[tid * 3 + 1] = pts[g * 3 + 1];
            sp1[tid * 3 + 2] = pts[g * 3 + 2];
        }
        if (tid < 256) {
            int g = fi2[tid];
            sp2[tid * 3 + 0] = pts[g * 3 + 0];
            sp2[tid * 3 + 1] = pts[g * 3 + 1];
            sp2[tid * 3 + 2] = pts[g * 3 + 2];
        }
    } else {
        knn_edge_body(*reinterpret_cast<KnnSmem*>(raw), pts, ew1, eb1, ew2, eb2,
                      feats, blockIdx.x - 1);
    }
}

// ---------------------------------------------------------------------------
// Tail: all three MLPs in one launch (validated mlp numerics, verbatim).
// ---------------------------------------------------------------------------
__device__ __forceinline__ void mlp_body(
    const float* __restrict__ feats, const int* __restrict__ orig,
    const float* __restrict__ mw1, const float* __restrict__ mb1,
    const float* __restrict__ mw2, const float* __restrict__ mb2,
    float* __restrict__ outp, int pb) {
    __shared__ float sfl[64], h1l[128];
    const int t = threadIdx.x;
    for (int pl = 0; pl < 16; ++pl) {
        const int p = pb * 16 + pl;
        const int g = orig[p];
        if (t < 64) sfl[t] = feats[g * 64 + t];
        __syncthreads();
        if (t < 128) {
            float h = mb1[t];
            for (int dd = 0; dd < 64; ++dd)
                h = fmaf(sfl[dd], mw1[dd * 128 + t], h);
            h1l[t] = fmaxf(h, 0.0f);
        }
        __syncthreads();
        float o = mb2[t];
        for (int dd = 0; dd < 128; ++dd)
            o = fmaf(h1l[dd], mw2[dd * 256 + t], o);
        outp[p * 256 + t] = o;
        __syncthreads();
    }
}

__global__ __launch_bounds__(256) void tail_kernel(
    const float* __restrict__ feats,
    const int* __restrict__ fi0, const int* __restrict__ fi1,
    const int* __restrict__ fi2,
    const float* __restrict__ mw1, const float* __restrict__ mb1,
    const float* __restrict__ mw2, const float* __restrict__ mb2,
    float* __restrict__ out) {
    const int b = blockIdx.x;
    float* lf0 = out + 12288;
    float* lf1 = out + 1063936;
    float* lf2 = out + 1326848;
    if (b < 256) {
        mlp_body(feats, fi0, mw1 + 0 * 8192, mb1 + 0 * 128,
                 mw2 + 0 * 32768, mb2 + 0 * 256, lf0, b);
    } else if (b < 320) {
        mlp_body(feats, fi1, mw1 + 1 * 8192, mb1 + 1 * 128,
                 mw2 + 1 * 32768, mb2 + 1 * 256, lf1, b - 256);
    } else {
        mlp_body(feats, fi2, mw1 + 2 * 8192, mb1 + 2 * 128,
                 mw2 + 2 * 32768, mb2 + 2 * 256, lf2, b - 320);
    }
}

// ---------------------------------------------------------------------------
extern "C" void kernel_launch(void* const* d_in, const int* in_sizes, int n_in,
                              void* d_out, int out_size, void* d_ws, size_t ws_size,
                              hipStream_t stream) {
    const float* pts = (const float*)d_in[0];
    const float* ew1 = (const float*)d_in[1];
    const float* eb1 = (const float*)d_in[2];
    const float* ew2 = (const float*)d_in[3];
    const float* eb2 = (const float*)d_in[4];
    const float* mw1 = (const float*)d_in[5];  // (3,64,128)
    const float* mb1 = (const float*)d_in[6];  // (3,128)
    const float* mw2 = (const float*)d_in[7];  // (3,128,256)
    const float* mb2 = (const float*)d_in[8];  // (3,256)
    float* out = (float*)d_out;
    char* ws = (char*)d_ws;

    float* feats = (float*)(ws + 0);           // 16384*64*4 = 4 MB
    int* fi0 = (int*)(ws + 4194304);           // 4096 ints (original indices)
    int* fi1 = (int*)(ws + 4210688);           // 1024 ints (original indices)
    int* fi2 = (int*)(ws + 4214784);           // 256 ints  (original indices)

    float* sp0 = out + 0;
    float* sp1 = out + 1060864;
    float* sp2 = out + 1326080;

    mega_kernel<<<1 + N_PTS / 16, 1024, 0, stream>>>(pts, ew1, eb1, ew2, eb2, feats,
                                                     fi0, fi1, fi2, sp0, sp1, sp2);
    tail_kernel<<<336, 256, 0, stream>>>(feats, fi0, fi1, fi2, mw1, mb1, mw2, mb2, out);
}

// Round 3
// 8300.978 us; speedup vs baseline: 2.4934x; 1.6556x over previous
//
#include <hip/hip_runtime.h>
#include <cfloat>
#include <cstdint>

#define N_PTS 16384
#define KNN_K 16
#define KNN_TILE 512
#define CERT_EPS 3e-6f

// ---------------------------------------------------------------------------
// FPS shared block. Only x in LDS (64 KB); y,z,c in registers (48 VGPR at
// P=16, indexed solely by unrolled constants, never address-taken -> stays in
// VGPRs). Reduction slots: packed-key atomicMax spread over 16 slots (proven
// round-0 scheme), parity double-buffered. Certification counter packed as
// [count, winner_flag] in adjacent ints -> single b64 read.
// ---------------------------------------------------------------------------
struct FpsSmem {
    float sx[N_PTS];                 // x coords (y,z stay in registers)
    unsigned long long slots[2][16]; // packed (m1,~g), tid&15-spread, parity dbuf
    int cw2[2][2];                   // [par][0]=#threads m1>=thr, [1]=winner m2>=thr
    int cand_idx[64];
    int cand_cnt;
    int more_flag;
    double red_d[16];
};

// DPP move within rows (VALU pipe -- no DS). Full row/bank masks; rotation
// patterns have no invalid source lanes, old=v is a safe no-op filler.
template <int CTRL>
__device__ __forceinline__ unsigned dpp_mov_u32(unsigned v) {
    return (unsigned)__builtin_amdgcn_update_dpp((int)v, (int)v, CTRL, 0xF, 0xF, false);
}

// Cross-slot max over the 16 slot keys, entirely on the VALU pipe.
// Lane l holds slots[l&15]; row_ror:{1,2,4,8} windows cover all 16 slots;
// every lane (all 4 rows identical) converges to the global (M1, G1).
// u64 numeric compare == atomicMax total order (larger m1, tie -> smaller g).
__device__ __forceinline__ void cross_slot_reduce(unsigned long long k, float& M1, int& G1) {
    unsigned hi = (unsigned)(k >> 32), lo = (unsigned)k;
#define RSTEP(CTRL)                                          \
    {                                                        \
        const unsigned ohi = dpp_mov_u32<CTRL>(hi);          \
        const unsigned olo = dpp_mov_u32<CTRL>(lo);          \
        const bool b = (ohi > hi) || (ohi == hi && olo > lo);\
        hi = b ? ohi : hi;                                   \
        lo = b ? olo : lo;                                   \
    }
    RSTEP(0x121)  // row_ror:1
    RSTEP(0x122)  // row_ror:2
    RSTEP(0x124)  // row_ror:4
    RSTEP(0x128)  // row_ror:8
#undef RSTEP
    M1 = __uint_as_float(hi);
    G1 = (int)(~lo);
}

// ---------------------------------------------------------------------------
// FPS body. Distance-update numerics verbatim (fp32 fmaf form, per-thread
// top-2). Selection total order identical to validated atomicMax. Cert:
// fallback iff (#threads m1>=thr)>1 || winner_m2>=thr (verbatim round-0).
// fp64 fallback verbatim. Winner coords: x from LDS, y/z broadcast global
// loads (L1-resident pts), prefetched before barrier B.
// ---------------------------------------------------------------------------
template <int P, bool IND>
__device__ __forceinline__ void fps_body(FpsSmem& sm, const float* __restrict__ pts,
                                         const int* __restrict__ idx,
                                         int n_out, int* __restrict__ fi) {
    constexpr int T = 1024;
    constexpr int NW = T / 64;
    const int tid = threadIdx.x;
    const int wave = tid >> 6, lane = tid & 63;

    __syncthreads();  // guard smem reuse against the previous stage's reads

    if (tid < 32) sm.slots[tid >> 4][tid & 15] = 0ull;
    if (tid < 4) sm.cw2[tid >> 1][tid & 1] = 0;

    float yr[P], zr[P], c[P];
    const int g0 = IND ? idx[0] : 0;
    const float sx0 = pts[g0 * 3 + 0], sy0 = pts[g0 * 3 + 1], sz0 = pts[g0 * 3 + 2];
    if (tid == 0) fi[0] = g0;

    // prologue: load coords (x -> LDS, y/z -> regs), update vs sample 0
    float m1 = -1.0f, m2 = -1.0f;
    int g1 = 0x7fffffff;
#pragma unroll
    for (int q = 0; q < P; ++q) {
        const int g = tid + q * T;
        const int gg = IND ? idx[g] : g;
        const float x = pts[gg * 3 + 0];
        const float y = pts[gg * 3 + 1];
        const float z = pts[gg * 3 + 2];
        sm.sx[g] = x;
        yr[q] = y;
        zr[q] = z;
        const float dx = x - sx0, dy = y - sy0, dz = z - sz0;
        const float t = fmaf(dx, dx, fmaf(dy, dy, dz * dz));
        const float nc = fminf(FLT_MAX, t);
        c[q] = nc;
        const bool gt = nc > m1;
        m2 = fmaxf(m2, fminf(nc, m1));
        m1 = fmaxf(m1, nc);
        g1 = gt ? g : g1;
    }
    __syncthreads();  // init + sx visible before first posts
    {
        const unsigned long long key =
            ((unsigned long long)__float_as_uint(m1) << 32) |
            (unsigned long long)(~(unsigned)g1);
        atomicMax(&sm.slots[1][tid & 15], key);
    }

    for (int s = 1; s < n_out; ++s) {
        __syncthreads();  // barrier A: slot posts of this parity visible
        const int par = s & 1;

        const unsigned long long k0 = sm.slots[par][lane & 15];
        float M1;
        int G1;
        cross_slot_reduce(k0, M1, G1);
        const float thr = M1 - M1 * CERT_EPS;

        // prefetch winner coords: overlaps cert posts + barrier B
        int wg = G1;
        if (IND) wg = idx[G1];
        float nx = sm.sx[G1];
        float ny = pts[wg * 3 + 1];
        float nz = pts[wg * 3 + 2];

        // resets for the next iteration's parity (before barrier B; next
        // parity's posts happen only after barrier B -> race-free)
        if (tid < 16) sm.slots[par ^ 1][tid] = 0ull;
        if (tid == 0) { sm.cw2[par ^ 1][0] = 0; sm.cw2[par ^ 1][1] = 0; }

        // certification posts (validated semantics, new plumbing):
        // count of threads with m1>=thr via per-wave ballot + one atomicAdd;
        // winner thread (unique: disjoint point ownership) posts m2>=thr.
        const unsigned long long bal = __ballot(m1 >= thr);
        if (lane == 0) atomicAdd(&sm.cw2[par][0], (int)__popcll(bal));
        if (g1 == G1) sm.cw2[par][1] = (m2 >= thr) ? 1 : 0;

        __syncthreads();  // barrier B: cert posts visible
        const int2 tw = *reinterpret_cast<const int2*>(&sm.cw2[par][0]);
        const int total = tw.x, wfl = tw.y;

        if (total > 1 || wfl) {
            // ---- cooperative exact fp64 fallback (uniform branch, verbatim) ----
            unsigned miss = 0;
#pragma unroll
            for (int q = 0; q < P; ++q)
                if (c[q] >= thr) miss |= (1u << q);
            double BD = -1.0;
            int BG = 0x7fffffff;
            for (;;) {
                if (tid == 0) { sm.cand_cnt = 0; sm.more_flag = 0; }
                __syncthreads();
#pragma unroll
                for (int q = 0; q < P; ++q) {
                    if (miss & (1u << q)) {
                        int slot = atomicAdd(&sm.cand_cnt, 1);
                        if (slot < 64) {
                            sm.cand_idx[slot] = tid + q * T;
                            miss &= ~(1u << q);
                        } else {
                            sm.more_flag = 1;
                        }
                    }
                }
                __syncthreads();
                int ncand = sm.cand_cnt;
                if (ncand > 64) ncand = 64;
                for (int ci = 0; ci < ncand; ++ci) {
                    const int g = sm.cand_idx[ci];
                    const int gg = IND ? idx[g] : g;
                    const double qx = (double)pts[gg * 3 + 0];
                    const double qy = (double)pts[gg * 3 + 1];
                    const double qz = (double)pts[gg * 3 + 2];
                    double dmin = DBL_MAX;
                    for (int i = tid; i < s; i += T) {
                        const int h = fi[i];  // original index, any stage
                        double ddx = qx - (double)pts[h * 3 + 0];
                        double ddy = qy - (double)pts[h * 3 + 1];
                        double ddz = qz - (double)pts[h * 3 + 2];
                        double dd = ddx * ddx + ddy * ddy + ddz * ddz;
                        dmin = (dd < dmin) ? dd : dmin;
                    }
                    for (int off = 32; off; off >>= 1) {
                        double od = __shfl_xor(dmin, off);
                        dmin = (od < dmin) ? od : dmin;
                    }
                    if (lane == 0) sm.red_d[wave] = dmin;
                    __syncthreads();
                    double dall = sm.red_d[0];
#pragma unroll
                    for (int w = 1; w < NW; ++w) dall = (sm.red_d[w] < dall) ? sm.red_d[w] : dall;
                    if (dall > BD || (dall == BD && g < BG)) { BD = dall; BG = g; }
                    __syncthreads();
                }
                int mf = sm.more_flag;
                __syncthreads();
                if (!mf) break;
            }
            G1 = BG;
            wg = IND ? idx[G1] : G1;
            nx = pts[wg * 3 + 0];
            ny = pts[wg * 3 + 1];
            nz = pts[wg * 3 + 2];
        }

        if (tid == 0) fi[s] = wg;
        if (s == n_out - 1) break;

        // fused min-update + per-thread top-2 (validated numerics, verbatim)
        float nm1 = -1.0f, nm2 = -1.0f;
        int ng1 = 0x7fffffff;
#pragma unroll
        for (int q = 0; q < P; ++q) {
            const float dx = sm.sx[tid + q * T] - nx;
            const float dy = yr[q] - ny, dz = zr[q] - nz;
            const float t = fmaf(dx, dx, fmaf(dy, dy, dz * dz));
            const float nc = fminf(c[q], t);
            c[q] = nc;
            const bool gt = nc > nm1;
            nm2 = fmaxf(nm2, fminf(nc, nm1));
            nm1 = fmaxf(nm1, nc);
            ng1 = gt ? (tid + q * T) : ng1;
        }
        m1 = nm1; m2 = nm2; g1 = ng1;
        const unsigned long long key =
            ((unsigned long long)__float_as_uint(m1) << 32) |
            (unsigned long long)(~(unsigned)g1);
        atomicMax(&sm.slots[par ^ 1][tid & 15], key);
    }
}

// ---------------------------------------------------------------------------
// Fused KNN + EdgeConv body: 1024 threads = 16 waves = 16 query points.
// Per-wave fp64-exact top-16 (verbatim validated numerics), edgeconv inline.
// ---------------------------------------------------------------------------
struct KnnSmem {
    float sx[KNN_TILE], sy[KNN_TILE], sz[KNN_TILE];
    float w1[6 * 64], b1v[64], w2[64 * 64], b2v[64];
};

__device__ __forceinline__ void knn_edge_body(
    KnnSmem& sm, const float* __restrict__ pts,
    const float* __restrict__ ew1, const float* __restrict__ eb1,
    const float* __restrict__ ew2, const float* __restrict__ eb2,
    float* __restrict__ feats, int qb) {
    for (int t = threadIdx.x; t < 6 * 64; t += 1024) sm.w1[t] = ew1[t];
    for (int t = threadIdx.x; t < 64; t += 1024) { sm.b1v[t] = eb1[t]; sm.b2v[t] = eb2[t]; }
    for (int t = threadIdx.x; t < 64 * 64; t += 1024) sm.w2[t] = ew2[t];

    const int wave = threadIdx.x >> 6;
    const int lane = threadIdx.x & 63;
    const int qi = qb * 16 + wave;
    const double qxd = (double)pts[qi * 3 + 0];
    const double qyd = (double)pts[qi * 3 + 1];
    const double qzd = (double)pts[qi * 3 + 2];

    double ld[16];
    int li[16];
#pragma unroll
    for (int s = 0; s < 16; ++s) { ld[s] = DBL_MAX; li[s] = 0x7fffffff; }
    double md = DBL_MAX; int mj = 0x7fffffff; int mslot = 0;

    for (int t0 = 0; t0 < N_PTS; t0 += KNN_TILE) {
        __syncthreads();
        for (int t = threadIdx.x; t < KNN_TILE; t += 1024) {
            sm.sx[t] = pts[(t0 + t) * 3 + 0];
            sm.sy[t] = pts[(t0 + t) * 3 + 1];
            sm.sz[t] = pts[(t0 + t) * 3 + 2];
        }
        __syncthreads();
#pragma unroll
        for (int m = 0; m < KNN_TILE / 64; ++m) {
            const int cc = lane + m * 64;
            const int j = t0 + cc;
            if (j == qi) continue;  // diagonal excluded (d=inf in reference)
            double dx = qxd - (double)sm.sx[cc];
            double dy = qyd - (double)sm.sy[cc];
            double dz = qzd - (double)sm.sz[cc];
            double dd = dx * dx + dy * dy + dz * dz;
            if (dd < md || (dd == md && j < mj)) {
#pragma unroll
                for (int s = 0; s < 16; ++s)
                    if (s == mslot) { ld[s] = dd; li[s] = j; }
                md = -1.0; mj = -1; mslot = 0;
#pragma unroll
                for (int s = 0; s < 16; ++s) {
                    bool g = (ld[s] > md) || (ld[s] == md && li[s] > mj);
                    if (g) { md = ld[s]; mj = li[s]; mslot = s; }
                }
            }
        }
    }

    const float xi = pts[qi * 3], yi = pts[qi * 3 + 1], zi = pts[qi * 3 + 2];
    float acc = -FLT_MAX;
    for (int r = 0; r < KNN_K; ++r) {
        double cd = DBL_MAX; int cj = 0x7fffffff; int cs = 0;
#pragma unroll
        for (int s = 0; s < 16; ++s) {
            bool l = (ld[s] < cd) || (ld[s] == cd && li[s] < cj);
            if (l) { cd = ld[s]; cj = li[s]; cs = s; }
        }
        double wd = cd; int wj = cj;
        for (int off = 32; off; off >>= 1) {
            double od = __shfl_xor(wd, off);
            int oj = __shfl_xor(wj, off);
            if (od < wd || (od == wd && oj < wj)) { wd = od; wj = oj; }
        }
        if (cd == wd && cj == wj) {
#pragma unroll
            for (int s = 0; s < 16; ++s)
                if (s == cs) { ld[s] = DBL_MAX; li[s] = 0x7fffffff; }
        }
        const float xj = pts[wj * 3], yj = pts[wj * 3 + 1], zj = pts[wj * 3 + 2];
        const float f3 = xj - xi, f4 = yj - yi, f5 = zj - zi;
        float h1 = sm.b1v[lane];
        h1 = fmaf(xi, sm.w1[0 * 64 + lane], h1);
        h1 = fmaf(yi, sm.w1[1 * 64 + lane], h1);
        h1 = fmaf(zi, sm.w1[2 * 64 + lane], h1);
        h1 = fmaf(f3, sm.w1[3 * 64 + lane], h1);
        h1 = fmaf(f4, sm.w1[4 * 64 + lane], h1);
        h1 = fmaf(f5, sm.w1[5 * 64 + lane], h1);
        h1 = fmaxf(h1, 0.0f);
        float h2 = sm.b2v[lane];
        for (int d = 0; d < 64; ++d)
            h2 = fmaf(__shfl(h1, d), sm.w2[d * 64 + lane], h2);
        acc = fmaxf(acc, h2);
    }
    feats[qi * 64 + lane] = acc;
}

// ---------------------------------------------------------------------------
// Mega kernel: block 0 chains fps0 -> fps1 -> fps2 (x LDS-resident, y/z in
// regs; fi* = ORIGINAL indices) and writes sp0/sp1/sp2. Blocks 1..1024 =
// fused knn+edgeconv (hidden under fps). Union LDS ~66 KB.
// ---------------------------------------------------------------------------
__global__ __launch_bounds__(1024)
void mega_kernel(const float* __restrict__ pts,
                 const float* __restrict__ ew1, const float* __restrict__ eb1,
                 const float* __restrict__ ew2, const float* __restrict__ eb2,
                 float* __restrict__ feats,
                 int* __restrict__ fi0, int* __restrict__ fi1, int* __restrict__ fi2,
                 float* __restrict__ sp0, float* __restrict__ sp1,
                 float* __restrict__ sp2) {
    constexpr size_t SMEM_BYTES =
        sizeof(FpsSmem) > sizeof(KnnSmem) ? sizeof(FpsSmem) : sizeof(KnnSmem);
    __shared__ __align__(16) char raw[SMEM_BYTES];
    if (blockIdx.x == 0) {
        FpsSmem& sm = *reinterpret_cast<FpsSmem*>(raw);
        fps_body<16, false>(sm, pts, nullptr, 4096, fi0);
        fps_body<4, true>(sm, pts, fi0, 1024, fi1);
        fps_body<1, true>(sm, pts, fi1, 256, fi2);
        __syncthreads();
        const int tid = threadIdx.x;
        for (int t = tid; t < 4096; t += 1024) {
            int g = fi0[t];
            sp0[t * 3 + 0] = pts[g * 3 + 0];
            sp0[t * 3 + 1] = pts[g * 3 + 1];
            sp0[t * 3 + 2] = pts[g * 3 + 2];
        }
        if (tid < 1024) {
            int g = fi1[tid];
            sp1[tid * 3 + 0] = pts[g * 3 + 0];
            sp1[tid * 3 + 1] = pts[g * 3 + 1];
            sp1[tid * 3 + 2] = pts[g * 3 + 2];
        }
        if (tid < 256) {
            int g = fi2[tid];
            sp2[tid * 3 + 0] = pts[g * 3 + 0];
            sp2[tid * 3 + 1] = pts[g * 3 + 1];
            sp2[tid * 3 + 2] = pts[g * 3 + 2];
        }
    } else {
        knn_edge_body(*reinterpret_cast<KnnSmem*>(raw), pts, ew1, eb1, ew2, eb2,
                      feats, blockIdx.x - 1);
    }
}

// ---------------------------------------------------------------------------
// Tail: all three MLPs in one launch (validated mlp numerics, verbatim).
// ---------------------------------------------------------------------------
__device__ __forceinline__ void mlp_body(
    const float* __restrict__ feats, const int* __restrict__ orig,
    const float* __restrict__ mw1, const float* __restrict__ mb1,
    const float* __restrict__ mw2, const float* __restrict__ mb2,
    float* __restrict__ outp, int pb) {
    __shared__ float sfl[64], h1l[128];
    const int t = threadIdx.x;
    for (int pl = 0; pl < 16; ++pl) {
        const int p = pb * 16 + pl;
        const int g = orig[p];
        if (t < 64) sfl[t] = feats[g * 64 + t];
        __syncthreads();
        if (t < 128) {
            float h = mb1[t];
            for (int dd = 0; dd < 64; ++dd)
                h = fmaf(sfl[dd], mw1[dd * 128 + t], h);
            h1l[t] = fmaxf(h, 0.0f);
        }
        __syncthreads();
        float o = mb2[t];
        for (int dd = 0; dd < 128; ++dd)
            o = fmaf(h1l[dd], mw2[dd * 256 + t], o);
        outp[p * 256 + t] = o;
        __syncthreads();
    }
}

__global__ __launch_bounds__(256) void tail_kernel(
    const float* __restrict__ feats,
    const int* __restrict__ fi0, const int* __restrict__ fi1,
    const int* __restrict__ fi2,
    const float* __restrict__ mw1, const float* __restrict__ mb1,
    const float* __restrict__ mw2, const float* __restrict__ mb2,
    float* __restrict__ out) {
    const int b = blockIdx.x;
    float* lf0 = out + 12288;
    float* lf1 = out + 1063936;
    float* lf2 = out + 1326848;
    if (b < 256) {
        mlp_body(feats, fi0, mw1 + 0 * 8192, mb1 + 0 * 128,
                 mw2 + 0 * 32768, mb2 + 0 * 256, lf0, b);
    } else if (b < 320) {
        mlp_body(feats, fi1, mw1 + 1 * 8192, mb1 + 1 * 128,
                 mw2 + 1 * 32768, mb2 + 1 * 256, lf1, b - 256);
    } else {
        mlp_body(feats, fi2, mw1 + 2 * 8192, mb1 + 2 * 128,
                 mw2 + 2 * 32768, mb2 + 2 * 256, lf2, b - 320);
    }
}

// ---------------------------------------------------------------------------
extern "C" void kernel_launch(void* const* d_in, const int* in_sizes, int n_in,
                              void* d_out, int out_size, void* d_ws, size_t ws_size,
                              hipStream_t stream) {
    const float* pts = (const float*)d_in[0];
    const float* ew1 = (const float*)d_in[1];
    const float* eb1 = (const float*)d_in[2];
    const float* ew2 = (const float*)d_in[3];
    const float* eb2 = (const float*)d_in[4];
    const float* mw1 = (const float*)d_in[5];  // (3,64,128)
    const float* mb1 = (const float*)d_in[6];  // (3,128)
    const float* mw2 = (const float*)d_in[7];  // (3,128,256)
    const float* mb2 = (const float*)d_in[8];  // (3,256)
    float* out = (float*)d_out;
    char* ws = (char*)d_ws;

    float* feats = (float*)(ws + 0);           // 16384*64*4 = 4 MB
    int* fi0 = (int*)(ws + 4194304);           // 4096 ints (original indices)
    int* fi1 = (int*)(ws + 4210688);           // 1024 ints (original indices)
    int* fi2 = (int*)(ws + 4214784);           // 256 ints  (original indices)

    float* sp0 = out + 0;
    float* sp1 = out + 1060864;
    float* sp2 = out + 1326080;

    mega_kernel<<<1 + N_PTS / 16, 1024, 0, stream>>>(pts, ew1, eb1, ew2, eb2, feats,
                                                     fi0, fi1, fi2, sp0, sp1, sp2);
    tail_kernel<<<336, 256, 0, stream>>>(feats, fi0, fi1, fi2, mw1, mb1, mw2, mb2, out);
}

// Round 4
// 7460.757 us; speedup vs baseline: 2.7742x; 1.1126x over previous
//
#include <hip/hip_runtime.h>
#include <cfloat>
#include <cstdint>

#define N_PTS 16384
#define KNN_K 16
#define KNN_TILE 512
#define CERT_EPS 3e-6f

// ---------------------------------------------------------------------------
// FPS shared block. x in LDS (64 KB); y,z,c in registers. Reduction slots:
// packed-key atomicMax spread over 16 slots, parity double-buffered
// (validated round-3 scheme). Winner coords OWNER-PUBLISHED to sm.pub
// (round-0-validated mechanism) -> no global loads on the critical path.
// ---------------------------------------------------------------------------
struct FpsSmem {
    float sx[N_PTS];                 // x coords (y,z stay in registers)
    unsigned long long slots[2][16]; // packed (m1,~g), tid&15-spread, parity dbuf
    int cw2[2][2];                   // [par][0]=#threads m1>=thr, [1]=winner m2>=thr
    float4 pub;                      // winner xyz, owner-published each iter
    int cand_idx[64];
    int cand_cnt;
    int more_flag;
    double red_d[16];
};

// DPP move within rows (VALU pipe -- no DS). Full row/bank masks; rotation
// patterns have no invalid source lanes, old=v is a safe no-op filler.
template <int CTRL>
__device__ __forceinline__ unsigned dpp_mov_u32(unsigned v) {
    return (unsigned)__builtin_amdgcn_update_dpp((int)v, (int)v, CTRL, 0xF, 0xF, false);
}

// Cross-slot max over the 16 slot keys, entirely on the VALU pipe (validated
// round 3). u64 numeric compare == atomicMax total order (larger m1, tie ->
// smaller g). Every lane converges to the global (M1, G1).
__device__ __forceinline__ void cross_slot_reduce(unsigned long long k, float& M1, int& G1) {
    unsigned hi = (unsigned)(k >> 32), lo = (unsigned)k;
#define RSTEP(CTRL)                                          \
    {                                                        \
        const unsigned ohi = dpp_mov_u32<CTRL>(hi);          \
        const unsigned olo = dpp_mov_u32<CTRL>(lo);          \
        const bool b = (ohi > hi) || (ohi == hi && olo > lo);\
        hi = b ? ohi : hi;                                   \
        lo = b ? olo : lo;                                   \
    }
    RSTEP(0x121)  // row_ror:1
    RSTEP(0x122)  // row_ror:2
    RSTEP(0x124)  // row_ror:4
    RSTEP(0x128)  // row_ror:8
#undef RSTEP
    M1 = __uint_as_float(hi);
    G1 = (int)(~lo);
}

// ---------------------------------------------------------------------------
// FPS, single stage (4096 samples). By the FPS prefix property (proved for
// the reference's own fp32 arithmetic incl. argmax tie-break), stages 1/2
// are exact prefixes of stage 0 -> they are not computed at all.
// Distance-update numerics verbatim. Selection total order identical to
// validated atomicMax. Cert: fallback iff (#threads m1>=thr)>1 ||
// winner_m2>=thr (verbatim). fp64 fallback verbatim.
// ---------------------------------------------------------------------------
__device__ __forceinline__ void fps_run(FpsSmem& sm, const float* __restrict__ pts,
                                        int n_out, int* __restrict__ fi) {
    constexpr int T = 1024;
    constexpr int P = 16;
    constexpr int NW = T / 64;
    const int tid = threadIdx.x;
    const int wave = tid >> 6, lane = tid & 63;

    if (tid < 32) sm.slots[tid >> 4][tid & 15] = 0ull;
    if (tid < 4) sm.cw2[tid >> 1][tid & 1] = 0;

    float yr[P], zr[P], c[P];
    const float sx0 = pts[0], sy0 = pts[1], sz0 = pts[2];
    if (tid == 0) fi[0] = 0;

    // prologue: load coords (x -> LDS, y/z -> regs), update vs sample 0
    float m1 = -1.0f, m2 = -1.0f;
    int g1 = 0x7fffffff;
#pragma unroll
    for (int q = 0; q < P; ++q) {
        const int g = tid + q * T;
        const float x = pts[g * 3 + 0];
        const float y = pts[g * 3 + 1];
        const float z = pts[g * 3 + 2];
        sm.sx[g] = x;
        yr[q] = y;
        zr[q] = z;
        const float dx = x - sx0, dy = y - sy0, dz = z - sz0;
        const float t = fmaf(dx, dx, fmaf(dy, dy, dz * dz));
        const float nc = fminf(FLT_MAX, t);
        c[q] = nc;
        const bool gt = nc > m1;
        m2 = fmaxf(m2, fminf(nc, m1));
        m1 = fmaxf(m1, nc);
        g1 = gt ? g : g1;
    }
    __syncthreads();  // init + sx visible before first posts
    {
        const unsigned long long key =
            ((unsigned long long)__float_as_uint(m1) << 32) |
            (unsigned long long)(~(unsigned)g1);
        atomicMax(&sm.slots[1][tid & 15], key);
    }

    for (int s = 1; s < n_out; ++s) {
        __syncthreads();  // barrier A: slot posts of this parity visible
        const int par = s & 1;

        const unsigned long long k0 = sm.slots[par][lane & 15];
        float M1;
        int G1;
        cross_slot_reduce(k0, M1, G1);
        const float thr = M1 - M1 * CERT_EPS;

        // owner publication (round-0 mechanism): the unique owner thread of
        // the winning point posts its xyz (x from LDS, y/z from registers).
        if (g1 == G1) {
            const int qw = (G1 - tid) >> 10;  // /1024
            float yw = 0.0f, zw = 0.0f;
#pragma unroll
            for (int q = 0; q < P; ++q)
                if (q == qw) { yw = yr[q]; zw = zr[q]; }
            sm.pub = make_float4(sm.sx[G1], yw, zw, 0.0f);
        }

        // resets for the next iteration's parity (race-free: next parity's
        // posts happen only after barrier B)
        if (tid < 16) sm.slots[par ^ 1][tid] = 0ull;
        if (tid == 0) { sm.cw2[par ^ 1][0] = 0; sm.cw2[par ^ 1][1] = 0; }

        // certification posts (validated): count of threads with m1>=thr via
        // per-wave ballot + one atomicAdd; winner thread posts m2>=thr.
        const unsigned long long bal = __ballot(m1 >= thr);
        if (lane == 0) atomicAdd(&sm.cw2[par][0], (int)__popcll(bal));
        if (g1 == G1) sm.cw2[par][1] = (m2 >= thr) ? 1 : 0;

        __syncthreads();  // barrier B: pub + cert posts visible
        const int2 tw = *reinterpret_cast<const int2*>(&sm.cw2[par][0]);
        const int total = tw.x, wfl = tw.y;
        const float4 wc = sm.pub;
        float nx = wc.x, ny = wc.y, nz = wc.z;
        int wg = G1;

        if (total > 1 || wfl) {
            // ---- cooperative exact fp64 fallback (uniform branch, verbatim) ----
            unsigned miss = 0;
#pragma unroll
            for (int q = 0; q < P; ++q)
                if (c[q] >= thr) miss |= (1u << q);
            double BD = -1.0;
            int BG = 0x7fffffff;
            for (;;) {
                if (tid == 0) { sm.cand_cnt = 0; sm.more_flag = 0; }
                __syncthreads();
#pragma unroll
                for (int q = 0; q < P; ++q) {
                    if (miss & (1u << q)) {
                        int slot = atomicAdd(&sm.cand_cnt, 1);
                        if (slot < 64) {
                            sm.cand_idx[slot] = tid + q * T;
                            miss &= ~(1u << q);
                        } else {
                            sm.more_flag = 1;
                        }
                    }
                }
                __syncthreads();
                int ncand = sm.cand_cnt;
                if (ncand > 64) ncand = 64;
                for (int ci = 0; ci < ncand; ++ci) {
                    const int g = sm.cand_idx[ci];
                    const double qx = (double)pts[g * 3 + 0];
                    const double qy = (double)pts[g * 3 + 1];
                    const double qz = (double)pts[g * 3 + 2];
                    double dmin = DBL_MAX;
                    for (int i = tid; i < s; i += T) {
                        const int h = fi[i];
                        double ddx = qx - (double)pts[h * 3 + 0];
                        double ddy = qy - (double)pts[h * 3 + 1];
                        double ddz = qz - (double)pts[h * 3 + 2];
                        double dd = ddx * ddx + ddy * ddy + ddz * ddz;
                        dmin = (dd < dmin) ? dd : dmin;
                    }
                    for (int off = 32; off; off >>= 1) {
                        double od = __shfl_xor(dmin, off);
                        dmin = (od < dmin) ? od : dmin;
                    }
                    if (lane == 0) sm.red_d[wave] = dmin;
                    __syncthreads();
                    double dall = sm.red_d[0];
#pragma unroll
                    for (int w = 1; w < NW; ++w) dall = (sm.red_d[w] < dall) ? sm.red_d[w] : dall;
                    if (dall > BD || (dall == BD && g < BG)) { BD = dall; BG = g; }
                    __syncthreads();
                }
                int mf = sm.more_flag;
                __syncthreads();
                if (!mf) break;
            }
            wg = BG;
            nx = pts[wg * 3 + 0];
            ny = pts[wg * 3 + 1];
            nz = pts[wg * 3 + 2];
        }

        if (tid == 0) fi[s] = wg;
        if (s == n_out - 1) break;

        // fused min-update + per-thread top-2 (validated numerics, verbatim)
        float nm1 = -1.0f, nm2 = -1.0f;
        int ng1 = 0x7fffffff;
#pragma unroll
        for (int q = 0; q < P; ++q) {
            const float dx = sm.sx[tid + q * T] - nx;
            const float dy = yr[q] - ny, dz = zr[q] - nz;
            const float t = fmaf(dx, dx, fmaf(dy, dy, dz * dz));
            const float nc = fminf(c[q], t);
            c[q] = nc;
            const bool gt = nc > nm1;
            nm2 = fmaxf(nm2, fminf(nc, nm1));
            nm1 = fmaxf(nm1, nc);
            ng1 = gt ? (tid + q * T) : ng1;
        }
        m1 = nm1; m2 = nm2; g1 = ng1;
        const unsigned long long key =
            ((unsigned long long)__float_as_uint(m1) << 32) |
            (unsigned long long)(~(unsigned)g1);
        atomicMax(&sm.slots[par ^ 1][tid & 15], key);
    }
}

// ---------------------------------------------------------------------------
// Fused KNN + EdgeConv body: 1024 threads = 16 waves = 16 query points.
// Per-wave fp64-exact top-16 (verbatim validated numerics), edgeconv inline.
// ---------------------------------------------------------------------------
struct KnnSmem {
    float sx[KNN_TILE], sy[KNN_TILE], sz[KNN_TILE];
    float w1[6 * 64], b1v[64], w2[64 * 64], b2v[64];
};

__device__ __forceinline__ void knn_edge_body(
    KnnSmem& sm, const float* __restrict__ pts,
    const float* __restrict__ ew1, const float* __restrict__ eb1,
    const float* __restrict__ ew2, const float* __restrict__ eb2,
    float* __restrict__ feats, int qb) {
    for (int t = threadIdx.x; t < 6 * 64; t += 1024) sm.w1[t] = ew1[t];
    for (int t = threadIdx.x; t < 64; t += 1024) { sm.b1v[t] = eb1[t]; sm.b2v[t] = eb2[t]; }
    for (int t = threadIdx.x; t < 64 * 64; t += 1024) sm.w2[t] = ew2[t];

    const int wave = threadIdx.x >> 6;
    const int lane = threadIdx.x & 63;
    const int qi = qb * 16 + wave;
    const double qxd = (double)pts[qi * 3 + 0];
    const double qyd = (double)pts[qi * 3 + 1];
    const double qzd = (double)pts[qi * 3 + 2];

    double ld[16];
    int li[16];
#pragma unroll
    for (int s = 0; s < 16; ++s) { ld[s] = DBL_MAX; li[s] = 0x7fffffff; }
    double md = DBL_MAX; int mj = 0x7fffffff; int mslot = 0;

    for (int t0 = 0; t0 < N_PTS; t0 += KNN_TILE) {
        __syncthreads();
        for (int t = threadIdx.x; t < KNN_TILE; t += 1024) {
            sm.sx[t] = pts[(t0 + t) * 3 + 0];
            sm.sy[t] = pts[(t0 + t) * 3 + 1];
            sm.sz[t] = pts[(t0 + t) * 3 + 2];
        }
        __syncthreads();
#pragma unroll
        for (int m = 0; m < KNN_TILE / 64; ++m) {
            const int cc = lane + m * 64;
            const int j = t0 + cc;
            if (j == qi) continue;  // diagonal excluded (d=inf in reference)
            double dx = qxd - (double)sm.sx[cc];
            double dy = qyd - (double)sm.sy[cc];
            double dz = qzd - (double)sm.sz[cc];
            double dd = dx * dx + dy * dy + dz * dz;
            if (dd < md || (dd == md && j < mj)) {
#pragma unroll
                for (int s = 0; s < 16; ++s)
                    if (s == mslot) { ld[s] = dd; li[s] = j; }
                md = -1.0; mj = -1; mslot = 0;
#pragma unroll
                for (int s = 0; s < 16; ++s) {
                    bool g = (ld[s] > md) || (ld[s] == md && li[s] > mj);
                    if (g) { md = ld[s]; mj = li[s]; mslot = s; }
                }
            }
        }
    }

    const float xi = pts[qi * 3], yi = pts[qi * 3 + 1], zi = pts[qi * 3 + 2];
    float acc = -FLT_MAX;
    for (int r = 0; r < KNN_K; ++r) {
        double cd = DBL_MAX; int cj = 0x7fffffff; int cs = 0;
#pragma unroll
        for (int s = 0; s < 16; ++s) {
            bool l = (ld[s] < cd) || (ld[s] == cd && li[s] < cj);
            if (l) { cd = ld[s]; cj = li[s]; cs = s; }
        }
        double wd = cd; int wj = cj;
        for (int off = 32; off; off >>= 1) {
            double od = __shfl_xor(wd, off);
            int oj = __shfl_xor(wj, off);
            if (od < wd || (od == wd && oj < wj)) { wd = od; wj = oj; }
        }
        if (cd == wd && cj == wj) {
#pragma unroll
            for (int s = 0; s < 16; ++s)
                if (s == cs) { ld[s] = DBL_MAX; li[s] = 0x7fffffff; }
        }
        const float xj = pts[wj * 3], yj = pts[wj * 3 + 1], zj = pts[wj * 3 + 2];
        const float f3 = xj - xi, f4 = yj - yi, f5 = zj - zi;
        float h1 = sm.b1v[lane];
        h1 = fmaf(xi, sm.w1[0 * 64 + lane], h1);
        h1 = fmaf(yi, sm.w1[1 * 64 + lane], h1);
        h1 = fmaf(zi, sm.w1[2 * 64 + lane], h1);
        h1 = fmaf(f3, sm.w1[3 * 64 + lane], h1);
        h1 = fmaf(f4, sm.w1[4 * 64 + lane], h1);
        h1 = fmaf(f5, sm.w1[5 * 64 + lane], h1);
        h1 = fmaxf(h1, 0.0f);
        float h2 = sm.b2v[lane];
        for (int d = 0; d < 64; ++d)
            h2 = fmaf(__shfl(h1, d), sm.w2[d * 64 + lane], h2);
        acc = fmaxf(acc, h2);
    }
    feats[qi * 64 + lane] = acc;
}

// ---------------------------------------------------------------------------
// Mega kernel: block 0 runs the single FPS stage (prefix property: fi1/fi2
// are prefixes of fi0) and writes sp0/sp1/sp2 from the fi0 prefix. Blocks
// 1..1024 = fused knn+edgeconv (hidden under fps).
// ---------------------------------------------------------------------------
__global__ __launch_bounds__(1024)
void mega_kernel(const float* __restrict__ pts,
                 const float* __restrict__ ew1, const float* __restrict__ eb1,
                 const float* __restrict__ ew2, const float* __restrict__ eb2,
                 float* __restrict__ feats,
                 int* __restrict__ fi0,
                 float* __restrict__ sp0, float* __restrict__ sp1,
                 float* __restrict__ sp2) {
    constexpr size_t SMEM_BYTES =
        sizeof(FpsSmem) > sizeof(KnnSmem) ? sizeof(FpsSmem) : sizeof(KnnSmem);
    __shared__ __align__(16) char raw[SMEM_BYTES];
    if (blockIdx.x == 0) {
        FpsSmem& sm = *reinterpret_cast<FpsSmem*>(raw);
        fps_run(sm, pts, 4096, fi0);
        __syncthreads();
        const int tid = threadIdx.x;
        for (int t = tid; t < 4096; t += 1024) {
            const int g = fi0[t];
            const float x = pts[g * 3 + 0];
            const float y = pts[g * 3 + 1];
            const float z = pts[g * 3 + 2];
            sp0[t * 3 + 0] = x;
            sp0[t * 3 + 1] = y;
            sp0[t * 3 + 2] = z;
            if (t < 1024) {
                sp1[t * 3 + 0] = x;
                sp1[t * 3 + 1] = y;
                sp1[t * 3 + 2] = z;
            }
            if (t < 256) {
                sp2[t * 3 + 0] = x;
                sp2[t * 3 + 1] = y;
                sp2[t * 3 + 2] = z;
            }
        }
    } else {
        knn_edge_body(*reinterpret_cast<KnnSmem*>(raw), pts, ew1, eb1, ew2, eb2,
                      feats, blockIdx.x - 1);
    }
}

// ---------------------------------------------------------------------------
// Tail: all three MLPs in one launch (validated mlp numerics, verbatim).
// All stages index feats via fi0 prefixes (prefix property).
// ---------------------------------------------------------------------------
__device__ __forceinline__ void mlp_body(
    const float* __restrict__ feats, const int* __restrict__ orig,
    const float* __restrict__ mw1, const float* __restrict__ mb1,
    const float* __restrict__ mw2, const float* __restrict__ mb2,
    float* __restrict__ outp, int pb) {
    __shared__ float sfl[64], h1l[128];
    const int t = threadIdx.x;
    for (int pl = 0; pl < 16; ++pl) {
        const int p = pb * 16 + pl;
        const int g = orig[p];
        if (t < 64) sfl[t] = feats[g * 64 + t];
        __syncthreads();
        if (t < 128) {
            float h = mb1[t];
            for (int dd = 0; dd < 64; ++dd)
                h = fmaf(sfl[dd], mw1[dd * 128 + t], h);
            h1l[t] = fmaxf(h, 0.0f);
        }
        __syncthreads();
        float o = mb2[t];
        for (int dd = 0; dd < 128; ++dd)
            o = fmaf(h1l[dd], mw2[dd * 256 + t], o);
        outp[p * 256 + t] = o;
        __syncthreads();
    }
}

__global__ __launch_bounds__(256) void tail_kernel(
    const float* __restrict__ feats,
    const int* __restrict__ fi0,
    const float* __restrict__ mw1, const float* __restrict__ mb1,
    const float* __restrict__ mw2, const float* __restrict__ mb2,
    float* __restrict__ out) {
    const int b = blockIdx.x;
    float* lf0 = out + 12288;
    float* lf1 = out + 1063936;
    float* lf2 = out + 1326848;
    if (b < 256) {
        mlp_body(feats, fi0, mw1 + 0 * 8192, mb1 + 0 * 128,
                 mw2 + 0 * 32768, mb2 + 0 * 256, lf0, b);
    } else if (b < 320) {
        mlp_body(feats, fi0, mw1 + 1 * 8192, mb1 + 1 * 128,
                 mw2 + 1 * 32768, mb2 + 1 * 256, lf1, b - 256);
    } else {
        mlp_body(feats, fi0, mw1 + 2 * 8192, mb1 + 2 * 128,
                 mw2 + 2 * 32768, mb2 + 2 * 256, lf2, b - 320);
    }
}

// ---------------------------------------------------------------------------
extern "C" void kernel_launch(void* const* d_in, const int* in_sizes, int n_in,
                              void* d_out, int out_size, void* d_ws, size_t ws_size,
                              hipStream_t stream) {
    const float* pts = (const float*)d_in[0];
    const float* ew1 = (const float*)d_in[1];
    const float* eb1 = (const float*)d_in[2];
    const float* ew2 = (const float*)d_in[3];
    const float* eb2 = (const float*)d_in[4];
    const float* mw1 = (const float*)d_in[5];  // (3,64,128)
    const float* mb1 = (const float*)d_in[6];  // (3,128)
    const float* mw2 = (const float*)d_in[7];  // (3,128,256)
    const float* mb2 = (const float*)d_in[8];  // (3,256)
    float* out = (float*)d_out;
    char* ws = (char*)d_ws;

    float* feats = (float*)(ws + 0);           // 16384*64*4 = 4 MB
    int* fi0 = (int*)(ws + 4194304);           // 4096 ints (original indices)

    float* sp0 = out + 0;
    float* sp1 = out + 1060864;
    float* sp2 = out + 1326080;

    mega_kernel<<<1 + N_PTS / 16, 1024, 0, stream>>>(pts, ew1, eb1, ew2, eb2, feats,
                                                     fi0, sp0, sp1, sp2);
    tail_kernel<<<336, 256, 0, stream>>>(feats, fi0, mw1, mb1, mw2, mb2, out);
}

// Round 5
// 6845.281 us; speedup vs baseline: 3.0236x; 1.0899x over previous
//
#include <hip/hip_runtime.h>
#include <cfloat>
#include <cstdint>

#define N_PTS 16384
#define KNN_K 16
#define KNN_TILE 512
#define CERT_EPS 3e-6f

// ---------------------------------------------------------------------------
// FPS shared block. ALL coordinates (x,y,z) live in per-thread REGISTERS
// (xr/yr/zr[16], constant-indexed, never address-taken -> VGPRs; the round-1
// spill was caused by passing register arrays by pointer, not by residency).
// LDS holds only the reduction slots (~1 KB): packed-key atomicMax spread
// over 16 slots, parity double-buffered (validated round-3/4 scheme).
// ---------------------------------------------------------------------------
struct FpsSmem {
    unsigned long long slots[2][16]; // packed (m1,~g), tid&15-spread, parity dbuf
    int cw2[2][2];                   // [par][0]=#threads m1>=thr, [1]=winner m2>=thr
    float4 pub;                      // winner xyz, owner-published each iter
    int cand_idx[64];
    int cand_cnt;
    int more_flag;
    double red_d[16];
};

// DPP move within rows (VALU pipe -- no DS). Full row/bank masks; rotation
// patterns have no invalid source lanes, old=v is a safe no-op filler.
template <int CTRL>
__device__ __forceinline__ unsigned dpp_mov_u32(unsigned v) {
    return (unsigned)__builtin_amdgcn_update_dpp((int)v, (int)v, CTRL, 0xF, 0xF, false);
}

// Cross-slot max over the 16 slot keys, entirely on the VALU pipe (validated
// rounds 3/4). u64 numeric compare == atomicMax total order (larger m1,
// tie -> smaller g). Every lane converges to the global (M1, G1).
__device__ __forceinline__ void cross_slot_reduce(unsigned long long k, float& M1, int& G1) {
    unsigned hi = (unsigned)(k >> 32), lo = (unsigned)k;
#define RSTEP(CTRL)                                          \
    {                                                        \
        const unsigned ohi = dpp_mov_u32<CTRL>(hi);          \
        const unsigned olo = dpp_mov_u32<CTRL>(lo);          \
        const bool b = (ohi > hi) || (ohi == hi && olo > lo);\
        hi = b ? ohi : hi;                                   \
        lo = b ? olo : lo;                                   \
    }
    RSTEP(0x121)  // row_ror:1
    RSTEP(0x122)  // row_ror:2
    RSTEP(0x124)  // row_ror:4
    RSTEP(0x128)  // row_ror:8
#undef RSTEP
    M1 = __uint_as_float(hi);
    G1 = (int)(~lo);
}

// ---------------------------------------------------------------------------
// FPS, single stage (4096 samples; stages 1/2 are exact prefixes -- round-4
// validated). Distance-update numerics verbatim (fp32 fmaf form). Selection
// total order identical to validated atomicMax. Cert identical semantics:
// fallback iff (#threads m1>=thr)>1 || winner_m2>=thr, where winner_m2 is
// recomputed EXACTLY by the unique owner thread as max_{q != qw} c[q]
// (same value as the old running top-2's m2: fmax is assoc/comm, and
// excluding only the first-max slot preserves duplicate-max semantics).
// fp64 fallback verbatim.
// ---------------------------------------------------------------------------
__device__ __forceinline__ void fps_run(FpsSmem& sm, const float* __restrict__ pts,
                                        int n_out, int* __restrict__ fi) {
    constexpr int T = 1024;
    constexpr int P = 16;
    constexpr int NW = T / 64;
    const int tid = threadIdx.x;
    const int wave = tid >> 6, lane = tid & 63;

    if (tid < 32) sm.slots[tid >> 4][tid & 15] = 0ull;
    if (tid < 4) sm.cw2[tid >> 1][tid & 1] = 0;

    float xr[P], yr[P], zr[P], c[P];
    const float sx0 = pts[0], sy0 = pts[1], sz0 = pts[2];
    if (tid == 0) fi[0] = 0;

    // prologue: load coords into registers, update vs sample 0
    float m1 = -1.0f;
    int g1 = 0x7fffffff;
#pragma unroll
    for (int q = 0; q < P; ++q) {
        const int g = tid + q * T;
        const float x = pts[g * 3 + 0];
        const float y = pts[g * 3 + 1];
        const float z = pts[g * 3 + 2];
        xr[q] = x;
        yr[q] = y;
        zr[q] = z;
        const float dx = x - sx0, dy = y - sy0, dz = z - sz0;
        const float t = fmaf(dx, dx, fmaf(dy, dy, dz * dz));
        const float nc = fminf(FLT_MAX, t);
        c[q] = nc;
        const bool gt = nc > m1;
        m1 = fmaxf(m1, nc);
        g1 = gt ? g : g1;
    }
    __syncthreads();  // slot/cw2 init visible before first posts
    {
        const unsigned long long key =
            ((unsigned long long)__float_as_uint(m1) << 32) |
            (unsigned long long)(~(unsigned)g1);
        atomicMax(&sm.slots[1][tid & 15], key);
    }

    for (int s = 1; s < n_out; ++s) {
        __syncthreads();  // barrier A: slot posts of this parity visible
        const int par = s & 1;

        const unsigned long long k0 = sm.slots[par][lane & 15];
        float M1;
        int G1;
        cross_slot_reduce(k0, M1, G1);
        const float thr = M1 - M1 * CERT_EPS;

        // owner publication + winner-m2 cert post: the unique owner thread
        // of the winning point posts xyz (all from registers) and its exact
        // second max over its own c[] (excluding the argmax slot qw).
        if (g1 == G1) {
            const int qw = (G1 - tid) >> 10;  // /1024
            float xw = 0.0f, yw = 0.0f, zw = 0.0f, m2w = -1.0f;
#pragma unroll
            for (int q = 0; q < P; ++q) {
                if (q == qw) { xw = xr[q]; yw = yr[q]; zw = zr[q]; }
                else m2w = fmaxf(m2w, c[q]);
            }
            sm.pub = make_float4(xw, yw, zw, 0.0f);
            sm.cw2[par][1] = (m2w >= thr) ? 1 : 0;
        }

        // resets for the next iteration's parity (race-free: next parity's
        // posts happen only after barrier B)
        if (tid < 16) sm.slots[par ^ 1][tid] = 0ull;
        if (tid == 0) { sm.cw2[par ^ 1][0] = 0; sm.cw2[par ^ 1][1] = 0; }

        // cert count (validated): #threads with m1>=thr via per-wave ballot
        // + one atomicAdd per wave.
        const unsigned long long bal = __ballot(m1 >= thr);
        if (lane == 0) atomicAdd(&sm.cw2[par][0], (int)__popcll(bal));

        __syncthreads();  // barrier B: pub + cert posts visible
        const int2 tw = *reinterpret_cast<const int2*>(&sm.cw2[par][0]);
        const int total = tw.x, wfl = tw.y;
        const float4 wc = sm.pub;
        float nx = wc.x, ny = wc.y, nz = wc.z;
        int wg = G1;

        if (total > 1 || wfl) {
            // ---- cooperative exact fp64 fallback (uniform branch, verbatim) ----
            unsigned miss = 0;
#pragma unroll
            for (int q = 0; q < P; ++q)
                if (c[q] >= thr) miss |= (1u << q);
            double BD = -1.0;
            int BG = 0x7fffffff;
            for (;;) {
                if (tid == 0) { sm.cand_cnt = 0; sm.more_flag = 0; }
                __syncthreads();
#pragma unroll
                for (int q = 0; q < P; ++q) {
                    if (miss & (1u << q)) {
                        int slot = atomicAdd(&sm.cand_cnt, 1);
                        if (slot < 64) {
                            sm.cand_idx[slot] = tid + q * T;
                            miss &= ~(1u << q);
                        } else {
                            sm.more_flag = 1;
                        }
                    }
                }
                __syncthreads();
                int ncand = sm.cand_cnt;
                if (ncand > 64) ncand = 64;
                for (int ci = 0; ci < ncand; ++ci) {
                    const int g = sm.cand_idx[ci];
                    const double qx = (double)pts[g * 3 + 0];
                    const double qy = (double)pts[g * 3 + 1];
                    const double qz = (double)pts[g * 3 + 2];
                    double dmin = DBL_MAX;
                    for (int i = tid; i < s; i += T) {
                        const int h = fi[i];
                        double ddx = qx - (double)pts[h * 3 + 0];
                        double ddy = qy - (double)pts[h * 3 + 1];
                        double ddz = qz - (double)pts[h * 3 + 2];
                        double dd = ddx * ddx + ddy * ddy + ddz * ddz;
                        dmin = (dd < dmin) ? dd : dmin;
                    }
                    for (int off = 32; off; off >>= 1) {
                        double od = __shfl_xor(dmin, off);
                        dmin = (od < dmin) ? od : dmin;
                    }
                    if (lane == 0) sm.red_d[wave] = dmin;
                    __syncthreads();
                    double dall = sm.red_d[0];
#pragma unroll
                    for (int w = 1; w < NW; ++w) dall = (sm.red_d[w] < dall) ? sm.red_d[w] : dall;
                    if (dall > BD || (dall == BD && g < BG)) { BD = dall; BG = g; }
                    __syncthreads();
                }
                int mf = sm.more_flag;
                __syncthreads();
                if (!mf) break;
            }
            wg = BG;
            nx = pts[wg * 3 + 0];
            ny = pts[wg * 3 + 1];
            nz = pts[wg * 3 + 2];
        }

        if (tid == 0) fi[s] = wg;
        if (s == n_out - 1) break;

        // fused min-update + per-thread argmax (validated numerics; the m2
        // running track is removed -- winner m2 recomputed exactly above).
        float nm1 = -1.0f;
        int ng1 = 0x7fffffff;
#pragma unroll
        for (int q = 0; q < P; ++q) {
            const float dx = xr[q] - nx, dy = yr[q] - ny, dz = zr[q] - nz;
            const float t = fmaf(dx, dx, fmaf(dy, dy, dz * dz));
            const float nc = fminf(c[q], t);
            c[q] = nc;
            const bool gt = nc > nm1;
            nm1 = fmaxf(nm1, nc);
            ng1 = gt ? (tid + q * T) : ng1;
        }
        m1 = nm1; g1 = ng1;
        const unsigned long long key =
            ((unsigned long long)__float_as_uint(m1) << 32) |
            (unsigned long long)(~(unsigned)g1);
        atomicMax(&sm.slots[par ^ 1][tid & 15], key);
    }
}

// ---------------------------------------------------------------------------
// Fused KNN + EdgeConv body: 1024 threads = 16 waves = 16 query points.
// Per-wave fp64-exact top-16 (verbatim validated numerics), edgeconv inline.
// ---------------------------------------------------------------------------
struct KnnSmem {
    float sx[KNN_TILE], sy[KNN_TILE], sz[KNN_TILE];
    float w1[6 * 64], b1v[64], w2[64 * 64], b2v[64];
};

__device__ __forceinline__ void knn_edge_body(
    KnnSmem& sm, const float* __restrict__ pts,
    const float* __restrict__ ew1, const float* __restrict__ eb1,
    const float* __restrict__ ew2, const float* __restrict__ eb2,
    float* __restrict__ feats, int qb) {
    for (int t = threadIdx.x; t < 6 * 64; t += 1024) sm.w1[t] = ew1[t];
    for (int t = threadIdx.x; t < 64; t += 1024) { sm.b1v[t] = eb1[t]; sm.b2v[t] = eb2[t]; }
    for (int t = threadIdx.x; t < 64 * 64; t += 1024) sm.w2[t] = ew2[t];

    const int wave = threadIdx.x >> 6;
    const int lane = threadIdx.x & 63;
    const int qi = qb * 16 + wave;
    const double qxd = (double)pts[qi * 3 + 0];
    const double qyd = (double)pts[qi * 3 + 1];
    const double qzd = (double)pts[qi * 3 + 2];

    double ld[16];
    int li[16];
#pragma unroll
    for (int s = 0; s < 16; ++s) { ld[s] = DBL_MAX; li[s] = 0x7fffffff; }
    double md = DBL_MAX; int mj = 0x7fffffff; int mslot = 0;

    for (int t0 = 0; t0 < N_PTS; t0 += KNN_TILE) {
        __syncthreads();
        for (int t = threadIdx.x; t < KNN_TILE; t += 1024) {
            sm.sx[t] = pts[(t0 + t) * 3 + 0];
            sm.sy[t] = pts[(t0 + t) * 3 + 1];
            sm.sz[t] = pts[(t0 + t) * 3 + 2];
        }
        __syncthreads();
#pragma unroll
        for (int m = 0; m < KNN_TILE / 64; ++m) {
            const int cc = lane + m * 64;
            const int j = t0 + cc;
            if (j == qi) continue;  // diagonal excluded (d=inf in reference)
            double dx = qxd - (double)sm.sx[cc];
            double dy = qyd - (double)sm.sy[cc];
            double dz = qzd - (double)sm.sz[cc];
            double dd = dx * dx + dy * dy + dz * dz;
            if (dd < md || (dd == md && j < mj)) {
#pragma unroll
                for (int s = 0; s < 16; ++s)
                    if (s == mslot) { ld[s] = dd; li[s] = j; }
                md = -1.0; mj = -1; mslot = 0;
#pragma unroll
                for (int s = 0; s < 16; ++s) {
                    bool g = (ld[s] > md) || (ld[s] == md && li[s] > mj);
                    if (g) { md = ld[s]; mj = li[s]; mslot = s; }
                }
            }
        }
    }

    const float xi = pts[qi * 3], yi = pts[qi * 3 + 1], zi = pts[qi * 3 + 2];
    float acc = -FLT_MAX;
    for (int r = 0; r < KNN_K; ++r) {
        double cd = DBL_MAX; int cj = 0x7fffffff; int cs = 0;
#pragma unroll
        for (int s = 0; s < 16; ++s) {
            bool l = (ld[s] < cd) || (ld[s] == cd && li[s] < cj);
            if (l) { cd = ld[s]; cj = li[s]; cs = s; }
        }
        double wd = cd; int wj = cj;
        for (int off = 32; off; off >>= 1) {
            double od = __shfl_xor(wd, off);
            int oj = __shfl_xor(wj, off);
            if (od < wd || (od == wd && oj < wj)) { wd = od; wj = oj; }
        }
        if (cd == wd && cj == wj) {
#pragma unroll
            for (int s = 0; s < 16; ++s)
                if (s == cs) { ld[s] = DBL_MAX; li[s] = 0x7fffffff; }
        }
        const float xj = pts[wj * 3], yj = pts[wj * 3 + 1], zj = pts[wj * 3 + 2];
        const float f3 = xj - xi, f4 = yj - yi, f5 = zj - zi;
        float h1 = sm.b1v[lane];
        h1 = fmaf(xi, sm.w1[0 * 64 + lane], h1);
        h1 = fmaf(yi, sm.w1[1 * 64 + lane], h1);
        h1 = fmaf(zi, sm.w1[2 * 64 + lane], h1);
        h1 = fmaf(f3, sm.w1[3 * 64 + lane], h1);
        h1 = fmaf(f4, sm.w1[4 * 64 + lane], h1);
        h1 = fmaf(f5, sm.w1[5 * 64 + lane], h1);
        h1 = fmaxf(h1, 0.0f);
        float h2 = sm.b2v[lane];
        for (int d = 0; d < 64; ++d)
            h2 = fmaf(__shfl(h1, d), sm.w2[d * 64 + lane], h2);
        acc = fmaxf(acc, h2);
    }
    feats[qi * 64 + lane] = acc;
}

// ---------------------------------------------------------------------------
// Mega kernel: block 0 runs the single FPS stage (prefix property: fi1/fi2
// are prefixes of fi0) and writes sp0/sp1/sp2 from the fi0 prefix. Blocks
// 1..1024 = fused knn+edgeconv (hidden under fps). Union LDS ~24 KB.
// ---------------------------------------------------------------------------
__global__ __launch_bounds__(1024)
void mega_kernel(const float* __restrict__ pts,
                 const float* __restrict__ ew1, const float* __restrict__ eb1,
                 const float* __restrict__ ew2, const float* __restrict__ eb2,
                 float* __restrict__ feats,
                 int* __restrict__ fi0,
                 float* __restrict__ sp0, float* __restrict__ sp1,
                 float* __restrict__ sp2) {
    constexpr size_t SMEM_BYTES =
        sizeof(FpsSmem) > sizeof(KnnSmem) ? sizeof(FpsSmem) : sizeof(KnnSmem);
    __shared__ __align__(16) char raw[SMEM_BYTES];
    if (blockIdx.x == 0) {
        FpsSmem& sm = *reinterpret_cast<FpsSmem*>(raw);
        fps_run(sm, pts, 4096, fi0);
        __syncthreads();
        const int tid = threadIdx.x;
        for (int t = tid; t < 4096; t += 1024) {
            const int g = fi0[t];
            const float x = pts[g * 3 + 0];
            const float y = pts[g * 3 + 1];
            const float z = pts[g * 3 + 2];
            sp0[t * 3 + 0] = x;
            sp0[t * 3 + 1] = y;
            sp0[t * 3 + 2] = z;
            if (t < 1024) {
                sp1[t * 3 + 0] = x;
                sp1[t * 3 + 1] = y;
                sp1[t * 3 + 2] = z;
            }
            if (t < 256) {
                sp2[t * 3 + 0] = x;
                sp2[t * 3 + 1] = y;
                sp2[t * 3 + 2] = z;
            }
        }
    } else {
        knn_edge_body(*reinterpret_cast<KnnSmem*>(raw), pts, ew1, eb1, ew2, eb2,
                      feats, blockIdx.x - 1);
    }
}

// ---------------------------------------------------------------------------
// Tail: all three MLPs in one launch (validated mlp numerics, verbatim).
// All stages index feats via fi0 prefixes (prefix property).
// ---------------------------------------------------------------------------
__device__ __forceinline__ void mlp_body(
    const float* __restrict__ feats, const int* __restrict__ orig,
    const float* __restrict__ mw1, const float* __restrict__ mb1,
    const float* __restrict__ mw2, const float* __restrict__ mb2,
    float* __restrict__ outp, int pb) {
    __shared__ float sfl[64], h1l[128];
    const int t = threadIdx.x;
    for (int pl = 0; pl < 16; ++pl) {
        const int p = pb * 16 + pl;
        const int g = orig[p];
        if (t < 64) sfl[t] = feats[g * 64 + t];
        __syncthreads();
        if (t < 128) {
            float h = mb1[t];
            for (int dd = 0; dd < 64; ++dd)
                h = fmaf(sfl[dd], mw1[dd * 128 + t], h);
            h1l[t] = fmaxf(h, 0.0f);
        }
        __syncthreads();
        float o = mb2[t];
        for (int dd = 0; dd < 128; ++dd)
            o = fmaf(h1l[dd], mw2[dd * 256 + t], o);
        outp[p * 256 + t] = o;
        __syncthreads();
    }
}

__global__ __launch_bounds__(256) void tail_kernel(
    const float* __restrict__ feats,
    const int* __restrict__ fi0,
    const float* __restrict__ mw1, const float* __restrict__ mb1,
    const float* __restrict__ mw2, const float* __restrict__ mb2,
    float* __restrict__ out) {
    const int b = blockIdx.x;
    float* lf0 = out + 12288;
    float* lf1 = out + 1063936;
    float* lf2 = out + 1326848;
    if (b < 256) {
        mlp_body(feats, fi0, mw1 + 0 * 8192, mb1 + 0 * 128,
                 mw2 + 0 * 32768, mb2 + 0 * 256, lf0, b);
    } else if (b < 320) {
        mlp_body(feats, fi0, mw1 + 1 * 8192, mb1 + 1 * 128,
                 mw2 + 1 * 32768, mb2 + 1 * 256, lf1, b - 256);
    } else {
        mlp_body(feats, fi0, mw1 + 2 * 8192, mb1 + 2 * 128,
                 mw2 + 2 * 32768, mb2 + 2 * 256, lf2, b - 320);
    }
}

// ---------------------------------------------------------------------------
extern "C" void kernel_launch(void* const* d_in, const int* in_sizes, int n_in,
                              void* d_out, int out_size, void* d_ws, size_t ws_size,
                              hipStream_t stream) {
    const float* pts = (const float*)d_in[0];
    const float* ew1 = (const float*)d_in[1];
    const float* eb1 = (const float*)d_in[2];
    const float* ew2 = (const float*)d_in[3];
    const float* eb2 = (const float*)d_in[4];
    const float* mw1 = (const float*)d_in[5];  // (3,64,128)
    const float* mb1 = (const float*)d_in[6];  // (3,128)
    const float* mw2 = (const float*)d_in[7];  // (3,128,256)
    const float* mb2 = (const float*)d_in[8];  // (3,256)
    float* out = (float*)d_out;
    char* ws = (char*)d_ws;

    float* feats = (float*)(ws + 0);           // 16384*64*4 = 4 MB
    int* fi0 = (int*)(ws + 4194304);           // 4096 ints (original indices)

    float* sp0 = out + 0;
    float* sp1 = out + 1060864;
    float* sp2 = out + 1326080;

    mega_kernel<<<1 + N_PTS / 16, 1024, 0, stream>>>(pts, ew1, eb1, ew2, eb2, feats,
                                                     fi0, sp0, sp1, sp2);
    tail_kernel<<<336, 256, 0, stream>>>(feats, fi0, mw1, mb1, mw2, mb2, out);
}